// Round 5
// baseline (245.672 us; speedup 1.0000x reference)
//
#include <hip/hip_runtime.h>
#include <stdint.h>

#define DIMSZ 1024
#define NHEADS 16
#define HD 64
#define BB 2
#define L_IN 1536
#define L_CTX 256
#define NTOT 1792   // L_CTX + L_IN
#define MROWS 3584  // BB * NTOT
#define NSPLIT 4
#define KVSPAN (NTOT / NSPLIT)   // 448
#define NROWS_BH 57344           // 32 * NTOT

typedef __attribute__((ext_vector_type(8))) short bf16x8;
typedef __attribute__((ext_vector_type(4))) float f32x4;
typedef __attribute__((ext_vector_type(16))) float f32x16;

__device__ inline unsigned short f2bf(float f) {
    union { float f; unsigned u; } v; v.f = f;
    unsigned r = v.u + 0x7fffu + ((v.u >> 16) & 1u);
    return (unsigned short)(r >> 16);
}
__device__ inline float bf2f(unsigned short u) {
    union { float f; unsigned u; } v; v.u = ((unsigned)u) << 16; return v.f;
}

__device__ inline f32x4 zero4() {
    f32x4 v;
    #pragma unroll
    for (int i = 0; i < 4; i++) v[i] = 0.f;
    return v;
}
__device__ inline f32x16 zero16() {
    f32x16 v;
    #pragma unroll
    for (int i = 0; i < 16; i++) v[i] = 0.f;
    return v;
}

// async global->LDS, 16B per lane. LDS dest must be wave-uniform base + lane*16.
#define GLL16(g, l) __builtin_amdgcn_global_load_lds( \
    (const __attribute__((address_space(1))) unsigned int*)(g), \
    (__attribute__((address_space(3))) unsigned int*)(l), 16, 0, 0)

// ---------------------------------------------------------------------------
// Pre-pass 1: convert activations fp32 -> bf16 into qkv row order.
// ---------------------------------------------------------------------------
__global__ __launch_bounds__(256) void conv_act(
    const float* __restrict__ input, const float* __restrict__ context,
    unsigned short* __restrict__ Abuf)
{
    int idx = blockIdx.x * 256 + threadIdx.x;
    int e = idx * 4;
    int row = e >> 10, c = e & 1023;
    int b = row / NTOT, ln = row % NTOT;
    const float* src = (ln < L_CTX)
        ? context + ((size_t)b * L_CTX + ln) * 1024 + c
        : input   + ((size_t)b * L_IN + (ln - L_CTX)) * 1024 + c;
    float4 v = *(const float4*)src;
    ushort4 o; o.x = f2bf(v.x); o.y = f2bf(v.y); o.z = f2bf(v.z); o.w = f2bf(v.w);
    *(ushort4*)(Abuf + e) = o;
}

// ---------------------------------------------------------------------------
// Pre-pass 2: W (1024 x N fp32, row-major) -> Wt (N x 1024 bf16, row-major).
// ---------------------------------------------------------------------------
__global__ __launch_bounds__(256) void transp(
    const float* __restrict__ W, unsigned short* __restrict__ Wt, int N)
{
    __shared__ unsigned short sm[64][65];
    int k0 = blockIdx.x * 64, n0 = blockIdx.y * 64;
    int t = threadIdx.x;
    #pragma unroll
    for (int i = 0; i < 4; i++) {
        int r = (t >> 4) + i * 16, c = (t & 15) * 4;
        float4 v = *(const float4*)(W + (size_t)(k0 + r) * N + n0 + c);
        sm[r][c] = f2bf(v.x); sm[r][c + 1] = f2bf(v.y);
        sm[r][c + 2] = f2bf(v.z); sm[r][c + 3] = f2bf(v.w);
    }
    __syncthreads();
    int rn = t & 63, kc = (t >> 6) * 16;
    unsigned short* dst = Wt + (size_t)(n0 + rn) * 1024 + k0 + kc;
    #pragma unroll
    for (int q = 0; q < 4; q++) {
        ushort4 o;
        o.x = sm[kc + q * 4 + 0][rn]; o.y = sm[kc + q * 4 + 1][rn];
        o.z = sm[kc + q * 4 + 2][rn]; o.w = sm[kc + q * 4 + 3][rn];
        *(ushort4*)(dst + q * 4) = o;
    }
}

// ---------------------------------------------------------------------------
// GEMM v2 (unchanged — verified): 128x128 tile, BK=64, global_load_lds
// staging with inverse-swizzled source + swizzled ds_read_b128 frags.
// ---------------------------------------------------------------------------
template<int NLD, bool OUT_BF16, bool IS_QKV>
__global__ __launch_bounds__(256, 4) void gemm2(
    const unsigned short* __restrict__ A,
    const unsigned short* __restrict__ Wt_in, const unsigned short* __restrict__ Wt_ctx,
    const float* __restrict__ bias_in, const float* __restrict__ bias_ctx,
    void* __restrict__ out_in_, void* __restrict__ out_ctx_)
{
    __shared__ __align__(16) unsigned short Asm[128 * 64];
    __shared__ __align__(16) unsigned short Bsm[128 * 64];
    const int rt = blockIdx.x, n0 = blockIdx.y * 128;
    const int b = rt / 14, lrt = rt % 14;
    const bool is_ctx = lrt < 2;
    const unsigned short* Wt = is_ctx ? Wt_ctx : Wt_in;
    const float* bias = is_ctx ? bias_ctx : bias_in;
    const int t = threadIdx.x, lane = t & 63, wid = t >> 6;
    const int wr = wid >> 1, wc = wid & 1;
    const int g4 = lane >> 4, l16 = lane & 15;

    const char* asrc[4]; const char* bsrc[4];
    #pragma unroll
    for (int j = 0; j < 4; j++) {
        int o = t * 16 + j * 4096;
        int row = o >> 7;
        int cb = (o & 127) ^ ((row & 7) << 4);
        asrc[j] = (const char*)A  + ((size_t)(rt * 128 + row)) * 2048 + cb;
        bsrc[j] = (const char*)Wt + ((size_t)(n0 + row)) * 2048 + cb;
    }

    f32x4 acc[4][4];
    #pragma unroll
    for (int mi = 0; mi < 4; mi++)
        #pragma unroll
        for (int ni = 0; ni < 4; ni++) acc[mi][ni] = zero4();

    for (int ks = 0; ks < 16; ks++) {
        __syncthreads();
        #pragma unroll
        for (int j = 0; j < 4; j++) {
            int o = t * 16 + j * 4096;
            GLL16(asrc[j], (char*)Asm + o);
            GLL16(bsrc[j], (char*)Bsm + o);
            asrc[j] += 128; bsrc[j] += 128;
        }
        __syncthreads();
        #pragma unroll
        for (int kk = 0; kk < 2; kk++) {
            bf16x8 a[4], bgf[4];
            #pragma unroll
            for (int mi = 0; mi < 4; mi++) {
                int row = wr * 64 + mi * 16 + l16;
                int byte = row * 128 + ((kk * 64 + g4 * 16) ^ ((row & 7) << 4));
                a[mi] = *(const bf16x8*)((const char*)Asm + byte);
            }
            #pragma unroll
            for (int ni = 0; ni < 4; ni++) {
                int col = wc * 64 + ni * 16 + l16;
                int byte = col * 128 + ((kk * 64 + g4 * 16) ^ ((col & 7) << 4));
                bgf[ni] = *(const bf16x8*)((const char*)Bsm + byte);
            }
            #pragma unroll
            for (int mi = 0; mi < 4; mi++)
                #pragma unroll
                for (int ni = 0; ni < 4; ni++)
                    acc[mi][ni] = __builtin_amdgcn_mfma_f32_16x16x32_bf16(
                        a[mi], bgf[ni], acc[mi][ni], 0, 0, 0);
        }
    }

    char* optr; size_t orow0;
    if constexpr (IS_QKV) {
        optr = (char*)out_in_; orow0 = (size_t)rt * 128;
    } else {
        if (is_ctx) { optr = (char*)out_ctx_; orow0 = (size_t)b * 256 + lrt * 128; }
        else        { optr = (char*)out_in_;  orow0 = (size_t)b * 1536 + (lrt - 2) * 128; }
    }
    #pragma unroll
    for (int mi = 0; mi < 4; mi++)
        #pragma unroll
        for (int ni = 0; ni < 4; ni++) {
            int col = n0 + wc * 64 + ni * 16 + l16;
            float bv = bias[col];
            #pragma unroll
            for (int r = 0; r < 4; r++) {
                size_t row = orow0 + wr * 64 + mi * 16 + g4 * 4 + r;
                float val = acc[mi][ni][r] + bv;
                if constexpr (OUT_BF16)
                    ((unsigned short*)optr)[row * NLD + col] = f2bf(val);
                else
                    ((float*)optr)[row * NLD + col] = val;
            }
        }
}

// ---------------------------------------------------------------------------
// Fused RMSNorm + weight + RoPE + scale + layout (unchanged).
// ---------------------------------------------------------------------------
__global__ __launch_bounds__(256) void norm_rope_kernel(
    const unsigned short* __restrict__ qkv,
    const float* __restrict__ qw_in, const float* __restrict__ kw_in,
    const float* __restrict__ qw_ctx, const float* __restrict__ kw_ctx,
    const float* __restrict__ cosT, const float* __restrict__ sinT,
    unsigned short* __restrict__ Q, unsigned short* __restrict__ K,
    unsigned short* __restrict__ Vt)
{
    int bn = blockIdx.x;
    int b = bn / NTOT, n = bn % NTOT;
    int t = threadIdx.x;
    const unsigned short* row = qkv + (size_t)bn * 3072;
    ushort4 qu = *(const ushort4*)(row + t * 4);
    ushort4 ku = *(const ushort4*)(row + 1024 + t * 4);
    ushort4 vu = *(const ushort4*)(row + 2048 + t * 4);
    float q0f = bf2f(qu.x), q1f = bf2f(qu.y), q2f = bf2f(qu.z), q3f = bf2f(qu.w);
    float k0f = bf2f(ku.x), k1f = bf2f(ku.y), k2f = bf2f(ku.z), k3f = bf2f(ku.w);
    float sq = q0f * q0f + q1f * q1f + q2f * q2f + q3f * q3f;
    float sk = k0f * k0f + k1f * k1f + k2f * k2f + k3f * k3f;
    #pragma unroll
    for (int m = 1; m < 64; m <<= 1) { sq += __shfl_xor(sq, m); sk += __shfl_xor(sk, m); }
    __shared__ float redq[4], redk[4];
    int lane = t & 63, w = t >> 6;
    if (lane == 0) { redq[w] = sq; redk[w] = sk; }
    __syncthreads();
    sq = redq[0] + redq[1] + redq[2] + redq[3];
    sk = redk[0] + redk[1] + redk[2] + redk[3];
    float rsq = rsqrtf(sq * (1.f / 1024.f) + 1e-6f);
    float rsk = rsqrtf(sk * (1.f / 1024.f) + 1e-6f);
    bool is_ctx = (n < L_CTX);
    const float* qw = is_ctx ? qw_ctx : qw_in;
    const float* kw = is_ctx ? kw_ctx : kw_in;
    int col = t * 4;
    int h = col >> 6, d = col & 63;
    float c0 = cosT[n * 32 + (d >> 1)],     s0 = sinT[n * 32 + (d >> 1)];
    float c1 = cosT[n * 32 + (d >> 1) + 1], s1 = sinT[n * 32 + (d >> 1) + 1];
    size_t base = (((size_t)(b * NHEADS + h)) * NTOT + n) * HD + d;
    {
        float x0 = q0f * rsq * qw[col],     x1 = q1f * rsq * qw[col + 1];
        float x2 = q2f * rsq * qw[col + 2], x3 = q3f * rsq * qw[col + 3];
        float y0 = x0 * c0 - x1 * s0, y1 = x0 * s0 + x1 * c0;
        float y2 = x2 * c1 - x3 * s1, y3 = x2 * s1 + x3 * c1;
        ushort4 o; o.x = f2bf(y0 * 0.125f); o.y = f2bf(y1 * 0.125f);
        o.z = f2bf(y2 * 0.125f); o.w = f2bf(y3 * 0.125f);
        *(ushort4*)(Q + base) = o;
    }
    {
        float x0 = k0f * rsk * kw[col],     x1 = k1f * rsk * kw[col + 1];
        float x2 = k2f * rsk * kw[col + 2], x3 = k3f * rsk * kw[col + 3];
        float y0 = x0 * c0 - x1 * s0, y1 = x0 * s0 + x1 * c0;
        float y2 = x2 * c1 - x3 * s1, y3 = x2 * s1 + x3 * c1;
        ushort4 o; o.x = f2bf(y0); o.y = f2bf(y1); o.z = f2bf(y2); o.w = f2bf(y3);
        *(ushort4*)(K + base) = o;
    }
    size_t vb = ((size_t)(b * NHEADS + h)) * HD;
    Vt[(vb + d + 0) * NTOT + n] = vu.x;
    Vt[(vb + d + 1) * NTOT + n] = vu.y;
    Vt[(vb + d + 2) * NTOT + n] = vu.z;
    Vt[(vb + d + 3) * NTOT + n] = vu.w;
}

// ---------------------------------------------------------------------------
// Flash attention v3: kv-split (NSPLIT=4). Grid (32 bh, 14 qt, 4 s).
// Each block: 448 keys, emits normalized bf16 partial O + (m,l) fp32 stats.
// Swapped operands: S^T = mfma(K, Q), lane owns q-row (lane&31).
// ---------------------------------------------------------------------------
__global__ __launch_bounds__(256) void attn_kernel(
    const unsigned short* __restrict__ Q, const unsigned short* __restrict__ K,
    const unsigned short* __restrict__ Vt, const int* __restrict__ mask,
    unsigned short* __restrict__ op0, unsigned short* __restrict__ op1,
    unsigned short* __restrict__ op2, unsigned short* __restrict__ op3,
    float* __restrict__ ms, float* __restrict__ ls)
{
    int bh = blockIdx.x;
    int b = bh >> 4, h = bh & 15;
    int s = blockIdx.z;
    int t = threadIdx.x, lane = t & 63, wid = t >> 6;
    int g = lane >> 5, lq = lane & 31;
    int q0 = blockIdx.y * 128 + wid * 32;
    __shared__ float mbias[L_CTX];
    if (t < L_CTX) mbias[t] = mask[b * L_CTX + t] ? 0.f : -1e30f;
    __syncthreads();
    const unsigned short* Qp = Q + (size_t)bh * NTOT * HD;
    const unsigned short* Kp = K + (size_t)bh * NTOT * HD;
    const unsigned short* Vp = Vt + (size_t)bh * HD * NTOT;

    bf16x8 qf[4];
    #pragma unroll
    for (int kk = 0; kk < 4; kk++)
        qf[kk] = *(const bf16x8*)(Qp + (size_t)(q0 + lq) * HD + kk * 16 + g * 8);

    f32x16 oacc0 = zero16(), oacc1 = zero16();
    float mrun = -1e30f, denom = 0.f;
    const int kvbeg = s * KVSPAN, kvend = kvbeg + KVSPAN;

    #pragma unroll 1
    for (int kv0 = kvbeg; kv0 < kvend; kv0 += 32) {
        const unsigned short* kb = Kp + (size_t)(kv0 + lq) * HD + g * 8;
        bf16x8 kf0 = *(const bf16x8*)(kb);
        bf16x8 kf1 = *(const bf16x8*)(kb + 16);
        bf16x8 kf2 = *(const bf16x8*)(kb + 32);
        bf16x8 kf3 = *(const bf16x8*)(kb + 48);
        const unsigned short* vp0 = Vp + (size_t)lq * NTOT + kv0 + g * 8;
        const unsigned short* vp1 = vp0 + (size_t)32 * NTOT;
        bf16x8 va0 = *(const bf16x8*)(vp0);
        bf16x8 va1 = *(const bf16x8*)(vp0 + 16);
        bf16x8 vb0 = *(const bf16x8*)(vp1);
        bf16x8 vb1 = *(const bf16x8*)(vp1 + 16);

        f32x16 st = zero16();
        st = __builtin_amdgcn_mfma_f32_32x32x16_bf16(kf0, qf[0], st, 0, 0, 0);
        st = __builtin_amdgcn_mfma_f32_32x32x16_bf16(kf1, qf[1], st, 0, 0, 0);
        st = __builtin_amdgcn_mfma_f32_32x32x16_bf16(kf2, qf[2], st, 0, 0, 0);
        st = __builtin_amdgcn_mfma_f32_32x32x16_bf16(kf3, qf[3], st, 0, 0, 0);
        if (kv0 < L_CTX) {
            #pragma unroll
            for (int r = 0; r < 16; r++) {
                int key = kv0 + (r & 3) + 8 * (r >> 2) + 4 * g;
                st[r] += mbias[key];
            }
        }
        float tmax = -1e30f;
        #pragma unroll
        for (int r = 0; r < 16; r++) tmax = fmaxf(tmax, st[r]);
        tmax = fmaxf(tmax, __shfl_xor(tmax, 32));
        if (!__all(tmax - mrun <= 8.f)) {
            float mnew = fmaxf(mrun, tmax);
            float corr = __expf(mrun - mnew);
            denom *= corr; mrun = mnew;
            #pragma unroll
            for (int i = 0; i < 16; i++) { oacc0[i] *= corr; oacc1[i] *= corr; }
        }
        float p[16];
        float psum = 0.f;
        #pragma unroll
        for (int r = 0; r < 16; r++) { p[r] = __expf(st[r] - mrun); psum += p[r]; }
        psum += __shfl_xor(psum, 32);
        denom += psum;
        bf16x8 pf[2];
        #pragma unroll
        for (int kk = 0; kk < 2; kk++) {
            unsigned a1, b1, a2, b2;
            asm("v_cvt_pk_bf16_f32 %0, %1, %2" : "=v"(a1) : "v"(p[8 * kk + 0]), "v"(p[8 * kk + 1]));
            asm("v_cvt_pk_bf16_f32 %0, %1, %2" : "=v"(a2) : "v"(p[8 * kk + 2]), "v"(p[8 * kk + 3]));
            asm("v_cvt_pk_bf16_f32 %0, %1, %2" : "=v"(b1) : "v"(p[8 * kk + 4]), "v"(p[8 * kk + 5]));
            asm("v_cvt_pk_bf16_f32 %0, %1, %2" : "=v"(b2) : "v"(p[8 * kk + 6]), "v"(p[8 * kk + 7]));
            unsigned sa1 = __shfl_xor(a1, 32), sb1 = __shfl_xor(b1, 32);
            unsigned sa2 = __shfl_xor(a2, 32), sb2 = __shfl_xor(b2, 32);
            unsigned d0 = g ? sb1 : a1;
            unsigned d1 = g ? sb2 : a2;
            unsigned d2 = g ? b1 : sa1;
            unsigned d3 = g ? b2 : sa2;
            union { unsigned u[4]; bf16x8 v; } pu;
            pu.u[0] = d0; pu.u[1] = d1; pu.u[2] = d2; pu.u[3] = d3;
            pf[kk] = pu.v;
        }
        oacc0 = __builtin_amdgcn_mfma_f32_32x32x16_bf16(va0, pf[0], oacc0, 0, 0, 0);
        oacc0 = __builtin_amdgcn_mfma_f32_32x32x16_bf16(va1, pf[1], oacc0, 0, 0, 0);
        oacc1 = __builtin_amdgcn_mfma_f32_32x32x16_bf16(vb0, pf[0], oacc1, 0, 0, 0);
        oacc1 = __builtin_amdgcn_mfma_f32_32x32x16_bf16(vb1, pf[1], oacc1, 0, 0, 0);
    }

    float inv = (denom > 0.f) ? 1.0f / denom : 0.f;
    int n = q0 + lq;
    int prow = bh * NTOT + n;
    unsigned short* op = (s == 0) ? op0 : (s == 1) ? op1 : (s == 2) ? op2 : op3;
    size_t obase = (size_t)prow * 64;
    #pragma unroll
    for (int r = 0; r < 16; r++) {
        int d = (r & 3) + 8 * (r >> 2) + 4 * g;
        op[obase + d] = f2bf(oacc0[r] * inv);
        op[obase + 32 + d] = f2bf(oacc1[r] * inv);
    }
    if (g == 0) {
        ms[s * NROWS_BH + prow] = mrun;
        ls[s * NROWS_BH + prow] = denom;
    }
}

// ---------------------------------------------------------------------------
// Merge NSPLIT partials -> Ob bf16 (B, NTOT, 1024).
// One thread per (bh,n, 4-wide d group). grid = 57344*16/256 = 3584.
// ---------------------------------------------------------------------------
__global__ __launch_bounds__(256) void attn_merge(
    const unsigned short* __restrict__ op0, const unsigned short* __restrict__ op1,
    const unsigned short* __restrict__ op2, const unsigned short* __restrict__ op3,
    const float* __restrict__ ms, const float* __restrict__ ls,
    unsigned short* __restrict__ Ob)
{
    int u = blockIdx.x * 256 + threadIdx.x;
    int dg = u & 15, bhn = u >> 4;
    int bh = bhn / NTOT, n = bhn % NTOT;
    int b = bh >> 4, h = bh & 15;
    float m0 = ms[bhn], m1 = ms[NROWS_BH + bhn];
    float m2 = ms[2 * NROWS_BH + bhn], m3 = ms[3 * NROWS_BH + bhn];
    float l0 = ls[bhn], l1 = ls[NROWS_BH + bhn];
    float l2 = ls[2 * NROWS_BH + bhn], l3 = ls[3 * NROWS_BH + bhn];
    float M = fmaxf(fmaxf(m0, m1), fmaxf(m2, m3));
    float w0 = l0 * __expf(m0 - M), w1 = l1 * __expf(m1 - M);
    float w2 = l2 * __expf(m2 - M), w3 = l3 * __expf(m3 - M);
    float inv = 1.f / (w0 + w1 + w2 + w3);
    w0 *= inv; w1 *= inv; w2 *= inv; w3 *= inv;
    size_t ro = (size_t)bhn * 64 + dg * 4;
    ushort4 a0 = *(const ushort4*)(op0 + ro);
    ushort4 a1 = *(const ushort4*)(op1 + ro);
    ushort4 a2 = *(const ushort4*)(op2 + ro);
    ushort4 a3 = *(const ushort4*)(op3 + ro);
    ushort4 o;
    o.x = f2bf(w0 * bf2f(a0.x) + w1 * bf2f(a1.x) + w2 * bf2f(a2.x) + w3 * bf2f(a3.x));
    o.y = f2bf(w0 * bf2f(a0.y) + w1 * bf2f(a1.y) + w2 * bf2f(a2.y) + w3 * bf2f(a3.y));
    o.z = f2bf(w0 * bf2f(a0.z) + w1 * bf2f(a1.z) + w2 * bf2f(a2.z) + w3 * bf2f(a3.z));
    o.w = f2bf(w0 * bf2f(a0.w) + w1 * bf2f(a1.w) + w2 * bf2f(a2.w) + w3 * bf2f(a3.w));
    size_t ob = ((size_t)(b * NTOT + n)) * 1024 + h * 64 + dg * 4;
    *(ushort4*)(Ob + ob) = o;
}

// ---------------------------------------------------------------------------
extern "C" void kernel_launch(void* const* d_in, const int* in_sizes, int n_in,
                              void* d_out, int out_size, void* d_ws, size_t ws_size,
                              hipStream_t stream) {
    const float* input    = (const float*)d_in[0];
    const float* context  = (const float*)d_in[1];
    const float* cosT     = (const float*)d_in[2];
    const float* sinT     = (const float*)d_in[3];
    const float* Wqkv_in  = (const float*)d_in[4];
    const float* bqkv_in  = (const float*)d_in[5];
    const float* Wqkv_ctx = (const float*)d_in[6];
    const float* bqkv_ctx = (const float*)d_in[7];
    const float* qw_in    = (const float*)d_in[8];
    const float* kw_in    = (const float*)d_in[9];
    const float* qw_ctx   = (const float*)d_in[10];
    const float* kw_ctx   = (const float*)d_in[11];
    const float* Wo_in    = (const float*)d_in[12];
    const float* bo_in    = (const float*)d_in[13];
    const float* Wo_ctx   = (const float*)d_in[14];
    const float* bo_ctx   = (const float*)d_in[15];
    const int*   mask     = (const int*)d_in[16];

    // ws layout (phases; aliased):
    //  0         WoT_in  (2,097,152)
    //  2,097,152 WoT_ctx (2,097,152)
    //  4,194,304 qkvb 22,020,096 [gemm->norm_rope]  ALIAS op0/op1/op2 (3x7,340,032)
    //  26,214,400 U: phase1 Abuf|WqT_in|WqT_ctx ; phase2 Qb|Kb|Vt|Ob
    //  55,574,528 op3 (7,340,032)
    //  62,914,560 ms (917,504) ; 63,832,064 ls (917,504); end 64,749,568
    char* ws = (char*)d_ws;
    unsigned short* WoT_in  = (unsigned short*)(ws);
    unsigned short* WoT_ctx = (unsigned short*)(ws + 2097152);
    unsigned short* qkvb    = (unsigned short*)(ws + 4194304);
    unsigned short* op0     = (unsigned short*)(ws + 4194304);
    unsigned short* op1     = (unsigned short*)(ws + 11534336);
    unsigned short* op2     = (unsigned short*)(ws + 18874368);
    char* U = ws + 26214400;
    unsigned short* Abuf    = (unsigned short*)(U);
    unsigned short* WqT_in  = (unsigned short*)(U + 7340032);
    unsigned short* WqT_ctx = (unsigned short*)(U + 13631488);
    unsigned short* Qb      = (unsigned short*)(U);
    unsigned short* Kb      = (unsigned short*)(U + 7340032);
    unsigned short* Vt      = (unsigned short*)(U + 14680064);
    unsigned short* Ob      = (unsigned short*)(U + 22020096);
    unsigned short* op3     = (unsigned short*)(ws + 55574528);
    float* msb              = (float*)(ws + 62914560);
    float* lsb              = (float*)(ws + 63832064);
    if (ws_size < 64749568) return; // loud failure instead of corruption

    float* out_in  = (float*)d_out;
    float* out_ctx = out_in + (size_t)BB * L_IN * DIMSZ;

    conv_act<<<MROWS, 256, 0, stream>>>(input, context, Abuf);
    transp<<<dim3(16, 48), 256, 0, stream>>>(Wqkv_in,  WqT_in,  3072);
    transp<<<dim3(16, 48), 256, 0, stream>>>(Wqkv_ctx, WqT_ctx, 3072);
    transp<<<dim3(16, 16), 256, 0, stream>>>(Wo_in,  WoT_in,  1024);
    transp<<<dim3(16, 16), 256, 0, stream>>>(Wo_ctx, WoT_ctx, 1024);

    gemm2<3072, true, true><<<dim3(28, 24), 256, 0, stream>>>(
        Abuf, WqT_in, WqT_ctx, bqkv_in, bqkv_ctx, qkvb, qkvb);

    norm_rope_kernel<<<MROWS, 256, 0, stream>>>(
        qkvb, qw_in, kw_in, qw_ctx, kw_ctx, cosT, sinT, Qb, Kb, Vt);

    attn_kernel<<<dim3(BB * NHEADS, NTOT / 128, NSPLIT), 256, 0, stream>>>(
        Qb, Kb, Vt, mask, op0, op1, op2, op3, msb, lsb);

    attn_merge<<<3584, 256, 0, stream>>>(op0, op1, op2, op3, msb, lsb, Ob);

    gemm2<1024, false, false><<<dim3(28, 8), 256, 0, stream>>>(
        Ob, WoT_in, WoT_ctx, bo_in, bo_ctx, out_in, out_ctx);
}

// Round 6
// 199.541 us; speedup vs baseline: 1.2312x; 1.2312x over previous
//
#include <hip/hip_runtime.h>
#include <stdint.h>

#define DIMSZ 1024
#define NHEADS 16
#define HD 64
#define BB 2
#define L_IN 1536
#define L_CTX 256
#define NTOT 1792   // L_CTX + L_IN
#define MROWS 3584  // BB * NTOT
#define NSPLIT 2
#define KVSPAN (NTOT / NSPLIT)   // 896
#define NT (KVSPAN / 32)         // 28 tiles per split
#define NROWS_BH 57344           // 32 * NTOT

typedef __attribute__((ext_vector_type(8))) short bf16x8;
typedef __attribute__((ext_vector_type(4))) float f32x4;
typedef __attribute__((ext_vector_type(16))) float f32x16;

__device__ inline unsigned short f2bf(float f) {
    union { float f; unsigned u; } v; v.f = f;
    unsigned r = v.u + 0x7fffu + ((v.u >> 16) & 1u);
    return (unsigned short)(r >> 16);
}
__device__ inline float bf2f(unsigned short u) {
    union { float f; unsigned u; } v; v.u = ((unsigned)u) << 16; return v.f;
}

__device__ inline f32x4 zero4() {
    f32x4 v;
    #pragma unroll
    for (int i = 0; i < 4; i++) v[i] = 0.f;
    return v;
}
__device__ inline f32x16 zero16() {
    f32x16 v;
    #pragma unroll
    for (int i = 0; i < 16; i++) v[i] = 0.f;
    return v;
}

// async global->LDS, 16B per lane. LDS dest must be wave-uniform base + lane*16.
#define GLL16(g, l) __builtin_amdgcn_global_load_lds( \
    (const __attribute__((address_space(1))) unsigned int*)(g), \
    (__attribute__((address_space(3))) unsigned int*)(l), 16, 0, 0)

// ---------------------------------------------------------------------------
// Pre-pass 1: convert activations fp32 -> bf16 into qkv row order.
// ---------------------------------------------------------------------------
__global__ __launch_bounds__(256) void conv_act(
    const float* __restrict__ input, const float* __restrict__ context,
    unsigned short* __restrict__ Abuf)
{
    int idx = blockIdx.x * 256 + threadIdx.x;
    int e = idx * 4;
    int row = e >> 10, c = e & 1023;
    int b = row / NTOT, ln = row % NTOT;
    const float* src = (ln < L_CTX)
        ? context + ((size_t)b * L_CTX + ln) * 1024 + c
        : input   + ((size_t)b * L_IN + (ln - L_CTX)) * 1024 + c;
    float4 v = *(const float4*)src;
    ushort4 o; o.x = f2bf(v.x); o.y = f2bf(v.y); o.z = f2bf(v.z); o.w = f2bf(v.w);
    *(ushort4*)(Abuf + e) = o;
}

// ---------------------------------------------------------------------------
// Pre-pass 2: W (1024 x N fp32, row-major) -> Wt (N x 1024 bf16, row-major).
// ---------------------------------------------------------------------------
__global__ __launch_bounds__(256) void transp(
    const float* __restrict__ W, unsigned short* __restrict__ Wt, int N)
{
    __shared__ unsigned short sm[64][65];
    int k0 = blockIdx.x * 64, n0 = blockIdx.y * 64;
    int t = threadIdx.x;
    #pragma unroll
    for (int i = 0; i < 4; i++) {
        int r = (t >> 4) + i * 16, c = (t & 15) * 4;
        float4 v = *(const float4*)(W + (size_t)(k0 + r) * N + n0 + c);
        sm[r][c] = f2bf(v.x); sm[r][c + 1] = f2bf(v.y);
        sm[r][c + 2] = f2bf(v.z); sm[r][c + 3] = f2bf(v.w);
    }
    __syncthreads();
    int rn = t & 63, kc = (t >> 6) * 16;
    unsigned short* dst = Wt + (size_t)(n0 + rn) * 1024 + k0 + kc;
    #pragma unroll
    for (int q = 0; q < 4; q++) {
        ushort4 o;
        o.x = sm[kc + q * 4 + 0][rn]; o.y = sm[kc + q * 4 + 1][rn];
        o.z = sm[kc + q * 4 + 2][rn]; o.w = sm[kc + q * 4 + 3][rn];
        *(ushort4*)(dst + q * 4) = o;
    }
}

// ---------------------------------------------------------------------------
// GEMM v2 (unchanged — verified): 128x128 tile, BK=64, global_load_lds
// staging with inverse-swizzled source + swizzled ds_read_b128 frags.
// ---------------------------------------------------------------------------
template<int NLD, bool OUT_BF16, bool IS_QKV>
__global__ __launch_bounds__(256, 4) void gemm2(
    const unsigned short* __restrict__ A,
    const unsigned short* __restrict__ Wt_in, const unsigned short* __restrict__ Wt_ctx,
    const float* __restrict__ bias_in, const float* __restrict__ bias_ctx,
    void* __restrict__ out_in_, void* __restrict__ out_ctx_)
{
    __shared__ __align__(16) unsigned short Asm[128 * 64];
    __shared__ __align__(16) unsigned short Bsm[128 * 64];
    const int rt = blockIdx.x, n0 = blockIdx.y * 128;
    const int b = rt / 14, lrt = rt % 14;
    const bool is_ctx = lrt < 2;
    const unsigned short* Wt = is_ctx ? Wt_ctx : Wt_in;
    const float* bias = is_ctx ? bias_ctx : bias_in;
    const int t = threadIdx.x, lane = t & 63, wid = t >> 6;
    const int wr = wid >> 1, wc = wid & 1;
    const int g4 = lane >> 4, l16 = lane & 15;

    const char* asrc[4]; const char* bsrc[4];
    #pragma unroll
    for (int j = 0; j < 4; j++) {
        int o = t * 16 + j * 4096;
        int row = o >> 7;
        int cb = (o & 127) ^ ((row & 7) << 4);
        asrc[j] = (const char*)A  + ((size_t)(rt * 128 + row)) * 2048 + cb;
        bsrc[j] = (const char*)Wt + ((size_t)(n0 + row)) * 2048 + cb;
    }

    f32x4 acc[4][4];
    #pragma unroll
    for (int mi = 0; mi < 4; mi++)
        #pragma unroll
        for (int ni = 0; ni < 4; ni++) acc[mi][ni] = zero4();

    for (int ks = 0; ks < 16; ks++) {
        __syncthreads();
        #pragma unroll
        for (int j = 0; j < 4; j++) {
            int o = t * 16 + j * 4096;
            GLL16(asrc[j], (char*)Asm + o);
            GLL16(bsrc[j], (char*)Bsm + o);
            asrc[j] += 128; bsrc[j] += 128;
        }
        __syncthreads();
        #pragma unroll
        for (int kk = 0; kk < 2; kk++) {
            bf16x8 a[4], bgf[4];
            #pragma unroll
            for (int mi = 0; mi < 4; mi++) {
                int row = wr * 64 + mi * 16 + l16;
                int byte = row * 128 + ((kk * 64 + g4 * 16) ^ ((row & 7) << 4));
                a[mi] = *(const bf16x8*)((const char*)Asm + byte);
            }
            #pragma unroll
            for (int ni = 0; ni < 4; ni++) {
                int col = wc * 64 + ni * 16 + l16;
                int byte = col * 128 + ((kk * 64 + g4 * 16) ^ ((col & 7) << 4));
                bgf[ni] = *(const bf16x8*)((const char*)Bsm + byte);
            }
            #pragma unroll
            for (int mi = 0; mi < 4; mi++)
                #pragma unroll
                for (int ni = 0; ni < 4; ni++)
                    acc[mi][ni] = __builtin_amdgcn_mfma_f32_16x16x32_bf16(
                        a[mi], bgf[ni], acc[mi][ni], 0, 0, 0);
        }
    }

    char* optr; size_t orow0;
    if constexpr (IS_QKV) {
        optr = (char*)out_in_; orow0 = (size_t)rt * 128;
    } else {
        if (is_ctx) { optr = (char*)out_ctx_; orow0 = (size_t)b * 256 + lrt * 128; }
        else        { optr = (char*)out_in_;  orow0 = (size_t)b * 1536 + (lrt - 2) * 128; }
    }
    #pragma unroll
    for (int mi = 0; mi < 4; mi++)
        #pragma unroll
        for (int ni = 0; ni < 4; ni++) {
            int col = n0 + wc * 64 + ni * 16 + l16;
            float bv = bias[col];
            #pragma unroll
            for (int r = 0; r < 4; r++) {
                size_t row = orow0 + wr * 64 + mi * 16 + g4 * 4 + r;
                float val = acc[mi][ni][r] + bv;
                if constexpr (OUT_BF16)
                    ((unsigned short*)optr)[row * NLD + col] = f2bf(val);
                else
                    ((float*)optr)[row * NLD + col] = val;
            }
        }
}

// ---------------------------------------------------------------------------
// Fused RMSNorm + weight + RoPE + scale + layout (unchanged).
// ---------------------------------------------------------------------------
__global__ __launch_bounds__(256) void norm_rope_kernel(
    const unsigned short* __restrict__ qkv,
    const float* __restrict__ qw_in, const float* __restrict__ kw_in,
    const float* __restrict__ qw_ctx, const float* __restrict__ kw_ctx,
    const float* __restrict__ cosT, const float* __restrict__ sinT,
    unsigned short* __restrict__ Q, unsigned short* __restrict__ K,
    unsigned short* __restrict__ Vt)
{
    int bn = blockIdx.x;
    int b = bn / NTOT, n = bn % NTOT;
    int t = threadIdx.x;
    const unsigned short* row = qkv + (size_t)bn * 3072;
    ushort4 qu = *(const ushort4*)(row + t * 4);
    ushort4 ku = *(const ushort4*)(row + 1024 + t * 4);
    ushort4 vu = *(const ushort4*)(row + 2048 + t * 4);
    float q0f = bf2f(qu.x), q1f = bf2f(qu.y), q2f = bf2f(qu.z), q3f = bf2f(qu.w);
    float k0f = bf2f(ku.x), k1f = bf2f(ku.y), k2f = bf2f(ku.z), k3f = bf2f(ku.w);
    float sq = q0f * q0f + q1f * q1f + q2f * q2f + q3f * q3f;
    float sk = k0f * k0f + k1f * k1f + k2f * k2f + k3f * k3f;
    #pragma unroll
    for (int m = 1; m < 64; m <<= 1) { sq += __shfl_xor(sq, m); sk += __shfl_xor(sk, m); }
    __shared__ float redq[4], redk[4];
    int lane = t & 63, w = t >> 6;
    if (lane == 0) { redq[w] = sq; redk[w] = sk; }
    __syncthreads();
    sq = redq[0] + redq[1] + redq[2] + redq[3];
    sk = redk[0] + redk[1] + redk[2] + redk[3];
    float rsq = rsqrtf(sq * (1.f / 1024.f) + 1e-6f);
    float rsk = rsqrtf(sk * (1.f / 1024.f) + 1e-6f);
    bool is_ctx = (n < L_CTX);
    const float* qw = is_ctx ? qw_ctx : qw_in;
    const float* kw = is_ctx ? kw_ctx : kw_in;
    int col = t * 4;
    int h = col >> 6, d = col & 63;
    float c0 = cosT[n * 32 + (d >> 1)],     s0 = sinT[n * 32 + (d >> 1)];
    float c1 = cosT[n * 32 + (d >> 1) + 1], s1 = sinT[n * 32 + (d >> 1) + 1];
    size_t base = (((size_t)(b * NHEADS + h)) * NTOT + n) * HD + d;
    {
        float x0 = q0f * rsq * qw[col],     x1 = q1f * rsq * qw[col + 1];
        float x2 = q2f * rsq * qw[col + 2], x3 = q3f * rsq * qw[col + 3];
        float y0 = x0 * c0 - x1 * s0, y1 = x0 * s0 + x1 * c0;
        float y2 = x2 * c1 - x3 * s1, y3 = x2 * s1 + x3 * c1;
        ushort4 o; o.x = f2bf(y0 * 0.125f); o.y = f2bf(y1 * 0.125f);
        o.z = f2bf(y2 * 0.125f); o.w = f2bf(y3 * 0.125f);
        *(ushort4*)(Q + base) = o;
    }
    {
        float x0 = k0f * rsk * kw[col],     x1 = k1f * rsk * kw[col + 1];
        float x2 = k2f * rsk * kw[col + 2], x3 = k3f * rsk * kw[col + 3];
        float y0 = x0 * c0 - x1 * s0, y1 = x0 * s0 + x1 * c0;
        float y2 = x2 * c1 - x3 * s1, y3 = x2 * s1 + x3 * c1;
        ushort4 o; o.x = f2bf(y0); o.y = f2bf(y1); o.z = f2bf(y2); o.w = f2bf(y3);
        *(ushort4*)(K + base) = o;
    }
    size_t vb = ((size_t)(b * NHEADS + h)) * HD;
    Vt[(vb + d + 0) * NTOT + n] = vu.x;
    Vt[(vb + d + 1) * NTOT + n] = vu.y;
    Vt[(vb + d + 2) * NTOT + n] = vu.z;
    Vt[(vb + d + 3) * NTOT + n] = vu.w;
}

// ---------------------------------------------------------------------------
// Flash attention v4: LDS-staged K/V tiles (coalesced global_load_lds, shared
// by all 4 waves), double-buffered; kv-split NSPLIT=2. Grid (32 bh, 14 qt, 2).
// K tile: 32 rows x 128B, XOR swizzle (row&7)<<4. V^T tile: 64 rows x 64B,
// XOR swizzle (row&3)<<4. Swapped-operand S^T = mfma(K,Q) as before.
// ---------------------------------------------------------------------------
__global__ __launch_bounds__(256) void attn_kernel(
    const unsigned short* __restrict__ Q, const unsigned short* __restrict__ K,
    const unsigned short* __restrict__ Vt, const int* __restrict__ mask,
    unsigned short* __restrict__ op0, unsigned short* __restrict__ op1,
    float* __restrict__ ms, float* __restrict__ ls)
{
    __shared__ __align__(16) char smem[2][8192];  // [buf][K 4KB | V 4KB]
    __shared__ float mbias[L_CTX];
    int bh = blockIdx.x;
    int b = bh >> 4, h = bh & 15;
    int s = blockIdx.z;
    int t = threadIdx.x, lane = t & 63, wid = t >> 6;
    int g = lane >> 5, lq = lane & 31;
    int q0 = blockIdx.y * 128 + wid * 32;

    const unsigned short* Qp = Q + (size_t)bh * NTOT * HD;
    const char* Kbase = (const char*)(K + (size_t)bh * NTOT * HD);
    const char* Vbase = (const char*)(Vt + (size_t)bh * HD * NTOT);
    const int kvbeg = s * KVSPAN;

    // staging addresses (inverse-swizzled global source, linear LDS dest)
    int krow = wid * 8 + (lane >> 3);
    int kcb  = ((lane & 7) * 16) ^ ((krow & 7) << 4);
    const char* ksrc = Kbase + (size_t)(kvbeg + krow) * 128 + kcb;
    int vrow = wid * 16 + (lane >> 2);
    int vslot = (lane & 3) ^ (vrow & 3);
    const char* vsrc = Vbase + (size_t)vrow * (NTOT * 2) + (size_t)kvbeg * 2 + vslot * 16;
    const int kdst = wid * 1024 + lane * 16;
    const int vdst = 4096 + wid * 1024 + lane * 16;

    // prologue: stage tile 0 into buf 0; mbias; one barrier covers both
    GLL16(ksrc, smem[0] + kdst);
    GLL16(vsrc, smem[0] + vdst);
    ksrc += 4096; vsrc += 64;
    if (t < L_CTX) mbias[t] = mask[b * L_CTX + t] ? 0.f : -1e30f;

    bf16x8 qf[4];
    #pragma unroll
    for (int kk = 0; kk < 4; kk++)
        qf[kk] = *(const bf16x8*)(Qp + (size_t)(q0 + lq) * HD + kk * 16 + g * 8);

    f32x16 oacc0 = zero16(), oacc1 = zero16();
    float mrun = -1e30f, denom = 0.f;

    __syncthreads();

    #pragma unroll 1
    for (int tt = 0; tt < NT; ++tt) {
        const char* cur = smem[tt & 1];
        char* nxt = smem[(tt & 1) ^ 1];
        if (tt + 1 < NT) {
            GLL16(ksrc, nxt + kdst);
            GLL16(vsrc, nxt + vdst);
            ksrc += 4096; vsrc += 64;
        }
        int kv0 = kvbeg + tt * 32;
        int ksw = (lq & 7) << 4;
        bf16x8 kf0 = *(const bf16x8*)(cur + lq * 128 + ((g * 16) ^ ksw));
        bf16x8 kf1 = *(const bf16x8*)(cur + lq * 128 + ((32 + g * 16) ^ ksw));
        bf16x8 kf2 = *(const bf16x8*)(cur + lq * 128 + ((64 + g * 16) ^ ksw));
        bf16x8 kf3 = *(const bf16x8*)(cur + lq * 128 + ((96 + g * 16) ^ ksw));
        const char* vc = cur + 4096;
        int vsw = (lq & 3) << 4;
        bf16x8 va0 = *(const bf16x8*)(vc + lq * 64 + ((g * 16) ^ vsw));
        bf16x8 va1 = *(const bf16x8*)(vc + lq * 64 + ((32 + g * 16) ^ vsw));
        bf16x8 vb0 = *(const bf16x8*)(vc + (lq + 32) * 64 + ((g * 16) ^ vsw));
        bf16x8 vb1 = *(const bf16x8*)(vc + (lq + 32) * 64 + ((32 + g * 16) ^ vsw));

        f32x16 st = zero16();
        st = __builtin_amdgcn_mfma_f32_32x32x16_bf16(kf0, qf[0], st, 0, 0, 0);
        st = __builtin_amdgcn_mfma_f32_32x32x16_bf16(kf1, qf[1], st, 0, 0, 0);
        st = __builtin_amdgcn_mfma_f32_32x32x16_bf16(kf2, qf[2], st, 0, 0, 0);
        st = __builtin_amdgcn_mfma_f32_32x32x16_bf16(kf3, qf[3], st, 0, 0, 0);
        if (kv0 < L_CTX) {
            #pragma unroll
            for (int r = 0; r < 16; r++) {
                int key = kv0 + (r & 3) + 8 * (r >> 2) + 4 * g;
                st[r] += mbias[key];
            }
        }
        float tmax = -1e30f;
        #pragma unroll
        for (int r = 0; r < 16; r++) tmax = fmaxf(tmax, st[r]);
        tmax = fmaxf(tmax, __shfl_xor(tmax, 32));
        if (!__all(tmax - mrun <= 8.f)) {
            float mnew = fmaxf(mrun, tmax);
            float corr = __expf(mrun - mnew);
            denom *= corr; mrun = mnew;
            #pragma unroll
            for (int i = 0; i < 16; i++) { oacc0[i] *= corr; oacc1[i] *= corr; }
        }
        float p[16];
        float psum = 0.f;
        #pragma unroll
        for (int r = 0; r < 16; r++) { p[r] = __expf(st[r] - mrun); psum += p[r]; }
        psum += __shfl_xor(psum, 32);
        denom += psum;
        bf16x8 pf[2];
        #pragma unroll
        for (int kk = 0; kk < 2; kk++) {
            unsigned a1, b1, a2, b2;
            asm("v_cvt_pk_bf16_f32 %0, %1, %2" : "=v"(a1) : "v"(p[8 * kk + 0]), "v"(p[8 * kk + 1]));
            asm("v_cvt_pk_bf16_f32 %0, %1, %2" : "=v"(a2) : "v"(p[8 * kk + 2]), "v"(p[8 * kk + 3]));
            asm("v_cvt_pk_bf16_f32 %0, %1, %2" : "=v"(b1) : "v"(p[8 * kk + 4]), "v"(p[8 * kk + 5]));
            asm("v_cvt_pk_bf16_f32 %0, %1, %2" : "=v"(b2) : "v"(p[8 * kk + 6]), "v"(p[8 * kk + 7]));
            unsigned sa1 = __shfl_xor(a1, 32), sb1 = __shfl_xor(b1, 32);
            unsigned sa2 = __shfl_xor(a2, 32), sb2 = __shfl_xor(b2, 32);
            unsigned d0 = g ? sb1 : a1;
            unsigned d1 = g ? sb2 : a2;
            unsigned d2 = g ? b1 : sa1;
            unsigned d3 = g ? b2 : sa2;
            union { unsigned u[4]; bf16x8 v; } pu;
            pu.u[0] = d0; pu.u[1] = d1; pu.u[2] = d2; pu.u[3] = d3;
            pf[kk] = pu.v;
        }
        oacc0 = __builtin_amdgcn_mfma_f32_32x32x16_bf16(va0, pf[0], oacc0, 0, 0, 0);
        oacc0 = __builtin_amdgcn_mfma_f32_32x32x16_bf16(va1, pf[1], oacc0, 0, 0, 0);
        oacc1 = __builtin_amdgcn_mfma_f32_32x32x16_bf16(vb0, pf[0], oacc1, 0, 0, 0);
        oacc1 = __builtin_amdgcn_mfma_f32_32x32x16_bf16(vb1, pf[1], oacc1, 0, 0, 0);
        __syncthreads();
    }

    float inv = (denom > 0.f) ? 1.0f / denom : 0.f;
    int n = q0 + lq;
    int prow = bh * NTOT + n;
    unsigned short* op = (s == 0) ? op0 : op1;
    size_t obase = (size_t)prow * 64;
    #pragma unroll
    for (int r = 0; r < 16; r++) {
        int d = (r & 3) + 8 * (r >> 2) + 4 * g;
        op[obase + d] = f2bf(oacc0[r] * inv);
        op[obase + 32 + d] = f2bf(oacc1[r] * inv);
    }
    if (g == 0) {
        ms[s * NROWS_BH + prow] = mrun;
        ls[s * NROWS_BH + prow] = denom;
    }
}

// ---------------------------------------------------------------------------
// Merge NSPLIT=2 partials -> Ob bf16 (B, NTOT, 1024). grid = 3584.
// ---------------------------------------------------------------------------
__global__ __launch_bounds__(256) void attn_merge(
    const unsigned short* __restrict__ op0, const unsigned short* __restrict__ op1,
    const float* __restrict__ ms, const float* __restrict__ ls,
    unsigned short* __restrict__ Ob)
{
    int u = blockIdx.x * 256 + threadIdx.x;
    int dg = u & 15, bhn = u >> 4;
    int bh = bhn / NTOT, n = bhn % NTOT;
    int b = bh >> 4, h = bh & 15;
    float m0 = ms[bhn], m1 = ms[NROWS_BH + bhn];
    float l0 = ls[bhn], l1 = ls[NROWS_BH + bhn];
    float M = fmaxf(m0, m1);
    float w0 = l0 * __expf(m0 - M), w1 = l1 * __expf(m1 - M);
    float inv = 1.f / (w0 + w1);
    w0 *= inv; w1 *= inv;
    size_t ro = (size_t)bhn * 64 + dg * 4;
    ushort4 a0 = *(const ushort4*)(op0 + ro);
    ushort4 a1 = *(const ushort4*)(op1 + ro);
    ushort4 o;
    o.x = f2bf(w0 * bf2f(a0.x) + w1 * bf2f(a1.x));
    o.y = f2bf(w0 * bf2f(a0.y) + w1 * bf2f(a1.y));
    o.z = f2bf(w0 * bf2f(a0.z) + w1 * bf2f(a1.z));
    o.w = f2bf(w0 * bf2f(a0.w) + w1 * bf2f(a1.w));
    size_t ob = ((size_t)(b * NTOT + n)) * 1024 + h * 64 + dg * 4;
    *(ushort4*)(Ob + ob) = o;
}

// ---------------------------------------------------------------------------
extern "C" void kernel_launch(void* const* d_in, const int* in_sizes, int n_in,
                              void* d_out, int out_size, void* d_ws, size_t ws_size,
                              hipStream_t stream) {
    const float* input    = (const float*)d_in[0];
    const float* context  = (const float*)d_in[1];
    const float* cosT     = (const float*)d_in[2];
    const float* sinT     = (const float*)d_in[3];
    const float* Wqkv_in  = (const float*)d_in[4];
    const float* bqkv_in  = (const float*)d_in[5];
    const float* Wqkv_ctx = (const float*)d_in[6];
    const float* bqkv_ctx = (const float*)d_in[7];
    const float* qw_in    = (const float*)d_in[8];
    const float* kw_in    = (const float*)d_in[9];
    const float* qw_ctx   = (const float*)d_in[10];
    const float* kw_ctx   = (const float*)d_in[11];
    const float* Wo_in    = (const float*)d_in[12];
    const float* bo_in    = (const float*)d_in[13];
    const float* Wo_ctx   = (const float*)d_in[14];
    const float* bo_ctx   = (const float*)d_in[15];
    const int*   mask     = (const int*)d_in[16];

    char* ws = (char*)d_ws;
    unsigned short* WoT_in  = (unsigned short*)(ws);
    unsigned short* WoT_ctx = (unsigned short*)(ws + 2097152);
    unsigned short* qkvb    = (unsigned short*)(ws + 4194304);
    unsigned short* op0     = (unsigned short*)(ws + 4194304);
    unsigned short* op1     = (unsigned short*)(ws + 11534336);
    char* U = ws + 26214400;
    unsigned short* Abuf    = (unsigned short*)(U);
    unsigned short* WqT_in  = (unsigned short*)(U + 7340032);
    unsigned short* WqT_ctx = (unsigned short*)(U + 13631488);
    unsigned short* Qb      = (unsigned short*)(U);
    unsigned short* Kb      = (unsigned short*)(U + 7340032);
    unsigned short* Vt      = (unsigned short*)(U + 14680064);
    unsigned short* Ob      = (unsigned short*)(U + 22020096);
    float* msb              = (float*)(ws + 62914560);
    float* lsb              = (float*)(ws + 63832064);
    if (ws_size < 64749568) return; // loud failure instead of corruption

    float* out_in  = (float*)d_out;
    float* out_ctx = out_in + (size_t)BB * L_IN * DIMSZ;

    conv_act<<<MROWS, 256, 0, stream>>>(input, context, Abuf);
    transp<<<dim3(16, 48), 256, 0, stream>>>(Wqkv_in,  WqT_in,  3072);
    transp<<<dim3(16, 48), 256, 0, stream>>>(Wqkv_ctx, WqT_ctx, 3072);
    transp<<<dim3(16, 16), 256, 0, stream>>>(Wo_in,  WoT_in,  1024);
    transp<<<dim3(16, 16), 256, 0, stream>>>(Wo_ctx, WoT_ctx, 1024);

    gemm2<3072, true, true><<<dim3(28, 24), 256, 0, stream>>>(
        Abuf, WqT_in, WqT_ctx, bqkv_in, bqkv_ctx, qkvb, qkvb);

    norm_rope_kernel<<<MROWS, 256, 0, stream>>>(
        qkvb, qw_in, kw_in, qw_ctx, kw_ctx, cosT, sinT, Qb, Kb, Vt);

    attn_kernel<<<dim3(BB * NHEADS, NTOT / 128, NSPLIT), 256, 0, stream>>>(
        Qb, Kb, Vt, mask, op0, op1, msb, lsb);

    attn_merge<<<3584, 256, 0, stream>>>(op0, op1, msb, lsb, Ob);

    gemm2<1024, false, false><<<dim3(28, 8), 256, 0, stream>>>(
        Ob, WoT_in, WoT_ctx, bo_in, bo_ctx, out_in, out_ctx);
}

// Round 7
// 199.096 us; speedup vs baseline: 1.2339x; 1.0022x over previous
//
#include <hip/hip_runtime.h>
#include <stdint.h>

#define DIMSZ 1024
#define NHEADS 16
#define HD 64
#define BB 2
#define L_IN 1536
#define L_CTX 256
#define NTOT 1792   // L_CTX + L_IN
#define MROWS 3584  // BB * NTOT
#define NSPLIT 2
#define KVSPAN (NTOT / NSPLIT)   // 896
#define NT64 (KVSPAN / 64)       // 14 tiles of 64 keys per split
#define NROWS_BH 57344           // 32 * NTOT

typedef __attribute__((ext_vector_type(8))) short bf16x8;
typedef __attribute__((ext_vector_type(4))) float f32x4;
typedef __attribute__((ext_vector_type(16))) float f32x16;

__device__ inline unsigned short f2bf(float f) {
    union { float f; unsigned u; } v; v.f = f;
    unsigned r = v.u + 0x7fffu + ((v.u >> 16) & 1u);
    return (unsigned short)(r >> 16);
}
__device__ inline float bf2f(unsigned short u) {
    union { float f; unsigned u; } v; v.u = ((unsigned)u) << 16; return v.f;
}

__device__ inline f32x4 zero4() {
    f32x4 v;
    #pragma unroll
    for (int i = 0; i < 4; i++) v[i] = 0.f;
    return v;
}
__device__ inline f32x16 zero16() {
    f32x16 v;
    #pragma unroll
    for (int i = 0; i < 16; i++) v[i] = 0.f;
    return v;
}

// async global->LDS, 16B per lane. LDS dest must be wave-uniform base + lane*16.
#define GLL16(g, l) __builtin_amdgcn_global_load_lds( \
    (const __attribute__((address_space(1))) unsigned int*)(g), \
    (__attribute__((address_space(3))) unsigned int*)(l), 16, 0, 0)

// ---------------------------------------------------------------------------
// Pre-pass 1: convert activations fp32 -> bf16 into qkv row order.
// ---------------------------------------------------------------------------
__global__ __launch_bounds__(256) void conv_act(
    const float* __restrict__ input, const float* __restrict__ context,
    unsigned short* __restrict__ Abuf)
{
    int idx = blockIdx.x * 256 + threadIdx.x;
    int e = idx * 4;
    int row = e >> 10, c = e & 1023;
    int b = row / NTOT, ln = row % NTOT;
    const float* src = (ln < L_CTX)
        ? context + ((size_t)b * L_CTX + ln) * 1024 + c
        : input   + ((size_t)b * L_IN + (ln - L_CTX)) * 1024 + c;
    float4 v = *(const float4*)src;
    ushort4 o; o.x = f2bf(v.x); o.y = f2bf(v.y); o.z = f2bf(v.z); o.w = f2bf(v.w);
    *(ushort4*)(Abuf + e) = o;
}

// ---------------------------------------------------------------------------
// Pre-pass 2: W (1024 x N fp32, row-major) -> Wt (N x 1024 bf16, row-major).
// ---------------------------------------------------------------------------
__global__ __launch_bounds__(256) void transp(
    const float* __restrict__ W, unsigned short* __restrict__ Wt, int N)
{
    __shared__ unsigned short sm[64][65];
    int k0 = blockIdx.x * 64, n0 = blockIdx.y * 64;
    int t = threadIdx.x;
    #pragma unroll
    for (int i = 0; i < 4; i++) {
        int r = (t >> 4) + i * 16, c = (t & 15) * 4;
        float4 v = *(const float4*)(W + (size_t)(k0 + r) * N + n0 + c);
        sm[r][c] = f2bf(v.x); sm[r][c + 1] = f2bf(v.y);
        sm[r][c + 2] = f2bf(v.z); sm[r][c + 3] = f2bf(v.w);
    }
    __syncthreads();
    int rn = t & 63, kc = (t >> 6) * 16;
    unsigned short* dst = Wt + (size_t)(n0 + rn) * 1024 + k0 + kc;
    #pragma unroll
    for (int q = 0; q < 4; q++) {
        ushort4 o;
        o.x = sm[kc + q * 4 + 0][rn]; o.y = sm[kc + q * 4 + 1][rn];
        o.z = sm[kc + q * 4 + 2][rn]; o.w = sm[kc + q * 4 + 3][rn];
        *(ushort4*)(dst + q * 4) = o;
    }
}

// ---------------------------------------------------------------------------
// GEMM v2 (unchanged — verified): 128x128 tile, BK=64, global_load_lds
// staging with inverse-swizzled source + swizzled ds_read_b128 frags.
// ---------------------------------------------------------------------------
template<int NLD, bool OUT_BF16, bool IS_QKV>
__global__ __launch_bounds__(256, 4) void gemm2(
    const unsigned short* __restrict__ A,
    const unsigned short* __restrict__ Wt_in, const unsigned short* __restrict__ Wt_ctx,
    const float* __restrict__ bias_in, const float* __restrict__ bias_ctx,
    void* __restrict__ out_in_, void* __restrict__ out_ctx_)
{
    __shared__ __align__(16) unsigned short Asm[128 * 64];
    __shared__ __align__(16) unsigned short Bsm[128 * 64];
    const int rt = blockIdx.x, n0 = blockIdx.y * 128;
    const int b = rt / 14, lrt = rt % 14;
    const bool is_ctx = lrt < 2;
    const unsigned short* Wt = is_ctx ? Wt_ctx : Wt_in;
    const float* bias = is_ctx ? bias_ctx : bias_in;
    const int t = threadIdx.x, lane = t & 63, wid = t >> 6;
    const int wr = wid >> 1, wc = wid & 1;
    const int g4 = lane >> 4, l16 = lane & 15;

    const char* asrc[4]; const char* bsrc[4];
    #pragma unroll
    for (int j = 0; j < 4; j++) {
        int o = t * 16 + j * 4096;
        int row = o >> 7;
        int cb = (o & 127) ^ ((row & 7) << 4);
        asrc[j] = (const char*)A  + ((size_t)(rt * 128 + row)) * 2048 + cb;
        bsrc[j] = (const char*)Wt + ((size_t)(n0 + row)) * 2048 + cb;
    }

    f32x4 acc[4][4];
    #pragma unroll
    for (int mi = 0; mi < 4; mi++)
        #pragma unroll
        for (int ni = 0; ni < 4; ni++) acc[mi][ni] = zero4();

    for (int ks = 0; ks < 16; ks++) {
        __syncthreads();
        #pragma unroll
        for (int j = 0; j < 4; j++) {
            int o = t * 16 + j * 4096;
            GLL16(asrc[j], (char*)Asm + o);
            GLL16(bsrc[j], (char*)Bsm + o);
            asrc[j] += 128; bsrc[j] += 128;
        }
        __syncthreads();
        #pragma unroll
        for (int kk = 0; kk < 2; kk++) {
            bf16x8 a[4], bgf[4];
            #pragma unroll
            for (int mi = 0; mi < 4; mi++) {
                int row = wr * 64 + mi * 16 + l16;
                int byte = row * 128 + ((kk * 64 + g4 * 16) ^ ((row & 7) << 4));
                a[mi] = *(const bf16x8*)((const char*)Asm + byte);
            }
            #pragma unroll
            for (int ni = 0; ni < 4; ni++) {
                int col = wc * 64 + ni * 16 + l16;
                int byte = col * 128 + ((kk * 64 + g4 * 16) ^ ((col & 7) << 4));
                bgf[ni] = *(const bf16x8*)((const char*)Bsm + byte);
            }
            #pragma unroll
            for (int mi = 0; mi < 4; mi++)
                #pragma unroll
                for (int ni = 0; ni < 4; ni++)
                    acc[mi][ni] = __builtin_amdgcn_mfma_f32_16x16x32_bf16(
                        a[mi], bgf[ni], acc[mi][ni], 0, 0, 0);
        }
    }

    char* optr; size_t orow0;
    if constexpr (IS_QKV) {
        optr = (char*)out_in_; orow0 = (size_t)rt * 128;
    } else {
        if (is_ctx) { optr = (char*)out_ctx_; orow0 = (size_t)b * 256 + lrt * 128; }
        else        { optr = (char*)out_in_;  orow0 = (size_t)b * 1536 + (lrt - 2) * 128; }
    }
    #pragma unroll
    for (int mi = 0; mi < 4; mi++)
        #pragma unroll
        for (int ni = 0; ni < 4; ni++) {
            int col = n0 + wc * 64 + ni * 16 + l16;
            float bv = bias[col];
            #pragma unroll
            for (int r = 0; r < 4; r++) {
                size_t row = orow0 + wr * 64 + mi * 16 + g4 * 4 + r;
                float val = acc[mi][ni][r] + bv;
                if constexpr (OUT_BF16)
                    ((unsigned short*)optr)[row * NLD + col] = f2bf(val);
                else
                    ((float*)optr)[row * NLD + col] = val;
            }
        }
}

// ---------------------------------------------------------------------------
// Fused RMSNorm + weight + RoPE + scale + layout.
// Q prescale now folds 0.125 * log2(e) (exp2-domain softmax downstream).
// ---------------------------------------------------------------------------
__global__ __launch_bounds__(256) void norm_rope_kernel(
    const unsigned short* __restrict__ qkv,
    const float* __restrict__ qw_in, const float* __restrict__ kw_in,
    const float* __restrict__ qw_ctx, const float* __restrict__ kw_ctx,
    const float* __restrict__ cosT, const float* __restrict__ sinT,
    unsigned short* __restrict__ Q, unsigned short* __restrict__ K,
    unsigned short* __restrict__ Vt)
{
    const float QSC = 0.125f * 1.44269504088896f;
    int bn = blockIdx.x;
    int b = bn / NTOT, n = bn % NTOT;
    int t = threadIdx.x;
    const unsigned short* row = qkv + (size_t)bn * 3072;
    ushort4 qu = *(const ushort4*)(row + t * 4);
    ushort4 ku = *(const ushort4*)(row + 1024 + t * 4);
    ushort4 vu = *(const ushort4*)(row + 2048 + t * 4);
    float q0f = bf2f(qu.x), q1f = bf2f(qu.y), q2f = bf2f(qu.z), q3f = bf2f(qu.w);
    float k0f = bf2f(ku.x), k1f = bf2f(ku.y), k2f = bf2f(ku.z), k3f = bf2f(ku.w);
    float sq = q0f * q0f + q1f * q1f + q2f * q2f + q3f * q3f;
    float sk = k0f * k0f + k1f * k1f + k2f * k2f + k3f * k3f;
    #pragma unroll
    for (int m = 1; m < 64; m <<= 1) { sq += __shfl_xor(sq, m); sk += __shfl_xor(sk, m); }
    __shared__ float redq[4], redk[4];
    int lane = t & 63, w = t >> 6;
    if (lane == 0) { redq[w] = sq; redk[w] = sk; }
    __syncthreads();
    sq = redq[0] + redq[1] + redq[2] + redq[3];
    sk = redk[0] + redk[1] + redk[2] + redk[3];
    float rsq = rsqrtf(sq * (1.f / 1024.f) + 1e-6f);
    float rsk = rsqrtf(sk * (1.f / 1024.f) + 1e-6f);
    bool is_ctx = (n < L_CTX);
    const float* qw = is_ctx ? qw_ctx : qw_in;
    const float* kw = is_ctx ? kw_ctx : kw_in;
    int col = t * 4;
    int h = col >> 6, d = col & 63;
    float c0 = cosT[n * 32 + (d >> 1)],     s0 = sinT[n * 32 + (d >> 1)];
    float c1 = cosT[n * 32 + (d >> 1) + 1], s1 = sinT[n * 32 + (d >> 1) + 1];
    size_t base = (((size_t)(b * NHEADS + h)) * NTOT + n) * HD + d;
    {
        float x0 = q0f * rsq * qw[col],     x1 = q1f * rsq * qw[col + 1];
        float x2 = q2f * rsq * qw[col + 2], x3 = q3f * rsq * qw[col + 3];
        float y0 = x0 * c0 - x1 * s0, y1 = x0 * s0 + x1 * c0;
        float y2 = x2 * c1 - x3 * s1, y3 = x2 * s1 + x3 * c1;
        ushort4 o; o.x = f2bf(y0 * QSC); o.y = f2bf(y1 * QSC);
        o.z = f2bf(y2 * QSC); o.w = f2bf(y3 * QSC);
        *(ushort4*)(Q + base) = o;
    }
    {
        float x0 = k0f * rsk * kw[col],     x1 = k1f * rsk * kw[col + 1];
        float x2 = k2f * rsk * kw[col + 2], x3 = k3f * rsk * kw[col + 3];
        float y0 = x0 * c0 - x1 * s0, y1 = x0 * s0 + x1 * c0;
        float y2 = x2 * c1 - x3 * s1, y3 = x2 * s1 + x3 * c1;
        ushort4 o; o.x = f2bf(y0); o.y = f2bf(y1); o.z = f2bf(y2); o.w = f2bf(y3);
        *(ushort4*)(K + base) = o;
    }
    size_t vb = ((size_t)(b * NHEADS + h)) * HD;
    Vt[(vb + d + 0) * NTOT + n] = vu.x;
    Vt[(vb + d + 1) * NTOT + n] = vu.y;
    Vt[(vb + d + 2) * NTOT + n] = vu.z;
    Vt[(vb + d + 3) * NTOT + n] = vu.w;
}

// ---------------------------------------------------------------------------
// Flash attention v5: 64-key tiles. K tile [64][128B] and V^T tile [64][128B]
// both XOR-8 swizzled (byte ^= (row&7)<<4), staged via global_load_lds with
// inverse-swizzled source. Static double-buffer (explicit buf0/buf1 bodies).
// exp2-domain softmax (log2e folded into Q). kv-split NSPLIT=2 + merge.
// ---------------------------------------------------------------------------
__global__ __launch_bounds__(256) void attn_kernel(
    const unsigned short* __restrict__ Q, const unsigned short* __restrict__ K,
    const unsigned short* __restrict__ Vt, const int* __restrict__ mask,
    unsigned short* __restrict__ op0, unsigned short* __restrict__ op1,
    float* __restrict__ ms, float* __restrict__ ls)
{
    // [buf0: K 8K | V 8K][buf1: K 8K | V 8K][mbias 1K]
    __shared__ __align__(16) char smem[33792];
    float* mbias = (float*)(smem + 32768);
    int bh = blockIdx.x;
    int b = bh >> 4;
    int s = blockIdx.z;
    int t = threadIdx.x, lane = t & 63, wid = t >> 6;
    int g = lane >> 5, lq = lane & 31;
    int q0 = blockIdx.y * 128 + wid * 32;

    const unsigned short* Qp = Q + (size_t)bh * NTOT * HD;
    const char* Kbase = (const char*)(K + (size_t)bh * NTOT * HD);
    const char* Vbase = (const char*)(Vt + (size_t)bh * HD * NTOT);
    const int kvbeg = s * KVSPAN;

    // staging: rows srow (chunk0) / srow+32 (chunk1); same in-row source byte.
    int srow = wid * 8 + (lane >> 3);
    int srcb = ((lane & 7) * 16) ^ ((lane >> 3) << 4);
    const char* ks0 = Kbase + (size_t)(kvbeg + srow) * 128 + srcb;
    const char* ks1 = ks0 + 32 * 128;
    const char* vs0 = Vbase + (size_t)srow * (NTOT * 2) + (size_t)kvbeg * 2 + srcb;
    const char* vs1 = vs0 + (size_t)32 * (NTOT * 2);
    const int sdst = wid * 1024 + lane * 16;

    auto stage = [&](int bufbase, int tt) {
        GLL16(ks0 + (size_t)tt * 8192, smem + bufbase + sdst);
        GLL16(ks1 + (size_t)tt * 8192, smem + bufbase + 4096 + sdst);
        GLL16(vs0 + (size_t)tt * 128,  smem + bufbase + 8192 + sdst);
        GLL16(vs1 + (size_t)tt * 128,  smem + bufbase + 8192 + 4096 + sdst);
    };

    stage(0, 0);
    if (t < L_CTX) mbias[t] = mask[b * L_CTX + t] ? 0.f : -1e30f;

    bf16x8 qf[4];
    #pragma unroll
    for (int kk = 0; kk < 4; kk++)
        qf[kk] = *(const bf16x8*)(Qp + (size_t)(q0 + lq) * HD + kk * 16 + g * 8);

    f32x16 oacc0 = zero16(), oacc1 = zero16();
    float mrun = -1e30f, denom = 0.f;
    const int ksw = (lq & 7) << 4;

    auto pack2 = [&](const f32x16& p, bf16x8* pfo) {
        #pragma unroll
        for (int kk = 0; kk < 2; kk++) {
            unsigned a1, b1, a2, b2;
            asm("v_cvt_pk_bf16_f32 %0, %1, %2" : "=v"(a1) : "v"(p[8 * kk + 0]), "v"(p[8 * kk + 1]));
            asm("v_cvt_pk_bf16_f32 %0, %1, %2" : "=v"(a2) : "v"(p[8 * kk + 2]), "v"(p[8 * kk + 3]));
            asm("v_cvt_pk_bf16_f32 %0, %1, %2" : "=v"(b1) : "v"(p[8 * kk + 4]), "v"(p[8 * kk + 5]));
            asm("v_cvt_pk_bf16_f32 %0, %1, %2" : "=v"(b2) : "v"(p[8 * kk + 6]), "v"(p[8 * kk + 7]));
            unsigned sa1 = __shfl_xor(a1, 32), sb1 = __shfl_xor(b1, 32);
            unsigned sa2 = __shfl_xor(a2, 32), sb2 = __shfl_xor(b2, 32);
            union { unsigned u[4]; bf16x8 v; } pu;
            pu.u[0] = g ? sb1 : a1;
            pu.u[1] = g ? sb2 : a2;
            pu.u[2] = g ? b1 : sa1;
            pu.u[3] = g ? b2 : sa2;
            pfo[kk] = pu.v;
        }
    };

    auto compute = [&](const char* bufK, const char* bufV, int kv0, bool msk) {
        f32x16 st0 = zero16(), st1 = zero16();
        #pragma unroll
        for (int kk = 0; kk < 4; kk++) {
            int off = (kk * 32 + g * 16) ^ ksw;
            bf16x8 kf0 = *(const bf16x8*)(bufK + lq * 128 + off);
            bf16x8 kf1 = *(const bf16x8*)(bufK + (lq + 32) * 128 + off);
            st0 = __builtin_amdgcn_mfma_f32_32x32x16_bf16(kf0, qf[kk], st0, 0, 0, 0);
            st1 = __builtin_amdgcn_mfma_f32_32x32x16_bf16(kf1, qf[kk], st1, 0, 0, 0);
        }
        if (msk) {
            #pragma unroll
            for (int r = 0; r < 16; r++) {
                int crow = (r & 3) + 8 * (r >> 2) + 4 * g;
                st0[r] += mbias[kv0 + crow];
                st1[r] += mbias[kv0 + 32 + crow];
            }
        }
        float tmax = -1e30f;
        #pragma unroll
        for (int r = 0; r < 16; r++) tmax = fmaxf(tmax, fmaxf(st0[r], st1[r]));
        tmax = fmaxf(tmax, __shfl_xor(tmax, 32));
        if (!__all(tmax - mrun <= 8.f)) {
            float mnew = fmaxf(mrun, tmax);
            float corr = exp2f(mrun - mnew);
            denom *= corr; mrun = mnew;
            #pragma unroll
            for (int i = 0; i < 16; i++) { oacc0[i] *= corr; oacc1[i] *= corr; }
        }
        float psum = 0.f;
        #pragma unroll
        for (int r = 0; r < 16; r++) { st0[r] = exp2f(st0[r] - mrun); psum += st0[r]; }
        #pragma unroll
        for (int r = 0; r < 16; r++) { st1[r] = exp2f(st1[r] - mrun); psum += st1[r]; }
        psum += __shfl_xor(psum, 32);
        denom += psum;
        bf16x8 pf[4];
        pack2(st0, pf);
        pack2(st1, pf + 2);
        #pragma unroll
        for (int kk = 0; kk < 4; kk++) {
            int off = (kk * 32 + g * 16) ^ ksw;
            bf16x8 va = *(const bf16x8*)(bufV + lq * 128 + off);
            bf16x8 vb = *(const bf16x8*)(bufV + (lq + 32) * 128 + off);
            oacc0 = __builtin_amdgcn_mfma_f32_32x32x16_bf16(va, pf[kk], oacc0, 0, 0, 0);
            oacc1 = __builtin_amdgcn_mfma_f32_32x32x16_bf16(vb, pf[kk], oacc1, 0, 0, 0);
        }
    };

    __syncthreads();

    #pragma unroll 1
    for (int it = 0; it < NT64 / 2; it++) {
        int tt = 2 * it;
        stage(16384, tt + 1);
        compute(smem, smem + 8192, kvbeg + tt * 64, (s == 0) && (tt < 4));
        __syncthreads();
        if (it != NT64 / 2 - 1) stage(0, tt + 2);
        compute(smem + 16384, smem + 24576, kvbeg + (tt + 1) * 64, (s == 0) && (tt + 1 < 4));
        __syncthreads();
    }

    float inv = (denom > 0.f) ? 1.0f / denom : 0.f;
    int n = q0 + lq;
    int prow = bh * NTOT + n;
    unsigned short* op = (s == 0) ? op0 : op1;
    size_t obase = (size_t)prow * 64;
    #pragma unroll
    for (int r = 0; r < 16; r++) {
        int d = (r & 3) + 8 * (r >> 2) + 4 * g;
        op[obase + d] = f2bf(oacc0[r] * inv);
        op[obase + 32 + d] = f2bf(oacc1[r] * inv);
    }
    if (g == 0) {
        ms[s * NROWS_BH + prow] = mrun;
        ls[s * NROWS_BH + prow] = denom;
    }
}

// ---------------------------------------------------------------------------
// Merge NSPLIT=2 partials -> Ob bf16 (B, NTOT, 1024). grid = 3584.
// Stats are in exp2 (log2) domain.
// ---------------------------------------------------------------------------
__global__ __launch_bounds__(256) void attn_merge(
    const unsigned short* __restrict__ op0, const unsigned short* __restrict__ op1,
    const float* __restrict__ ms, const float* __restrict__ ls,
    unsigned short* __restrict__ Ob)
{
    int u = blockIdx.x * 256 + threadIdx.x;
    int dg = u & 15, bhn = u >> 4;
    int bh = bhn / NTOT, n = bhn % NTOT;
    int b = bh >> 4, h = bh & 15;
    float m0 = ms[bhn], m1 = ms[NROWS_BH + bhn];
    float l0 = ls[bhn], l1 = ls[NROWS_BH + bhn];
    float M = fmaxf(m0, m1);
    float w0 = l0 * exp2f(m0 - M), w1 = l1 * exp2f(m1 - M);
    float inv = 1.f / (w0 + w1);
    w0 *= inv; w1 *= inv;
    size_t ro = (size_t)bhn * 64 + dg * 4;
    ushort4 a0 = *(const ushort4*)(op0 + ro);
    ushort4 a1 = *(const ushort4*)(op1 + ro);
    ushort4 o;
    o.x = f2bf(w0 * bf2f(a0.x) + w1 * bf2f(a1.x));
    o.y = f2bf(w0 * bf2f(a0.y) + w1 * bf2f(a1.y));
    o.z = f2bf(w0 * bf2f(a0.z) + w1 * bf2f(a1.z));
    o.w = f2bf(w0 * bf2f(a0.w) + w1 * bf2f(a1.w));
    size_t ob = ((size_t)(b * NTOT + n)) * 1024 + h * 64 + dg * 4;
    *(ushort4*)(Ob + ob) = o;
}

// ---------------------------------------------------------------------------
extern "C" void kernel_launch(void* const* d_in, const int* in_sizes, int n_in,
                              void* d_out, int out_size, void* d_ws, size_t ws_size,
                              hipStream_t stream) {
    const float* input    = (const float*)d_in[0];
    const float* context  = (const float*)d_in[1];
    const float* cosT     = (const float*)d_in[2];
    const float* sinT     = (const float*)d_in[3];
    const float* Wqkv_in  = (const float*)d_in[4];
    const float* bqkv_in  = (const float*)d_in[5];
    const float* Wqkv_ctx = (const float*)d_in[6];
    const float* bqkv_ctx = (const float*)d_in[7];
    const float* qw_in    = (const float*)d_in[8];
    const float* kw_in    = (const float*)d_in[9];
    const float* qw_ctx   = (const float*)d_in[10];
    const float* kw_ctx   = (const float*)d_in[11];
    const float* Wo_in    = (const float*)d_in[12];
    const float* bo_in    = (const float*)d_in[13];
    const float* Wo_ctx   = (const float*)d_in[14];
    const float* bo_ctx   = (const float*)d_in[15];
    const int*   mask     = (const int*)d_in[16];

    char* ws = (char*)d_ws;
    unsigned short* WoT_in  = (unsigned short*)(ws);
    unsigned short* WoT_ctx = (unsigned short*)(ws + 2097152);
    unsigned short* qkvb    = (unsigned short*)(ws + 4194304);
    unsigned short* op0     = (unsigned short*)(ws + 4194304);
    unsigned short* op1     = (unsigned short*)(ws + 11534336);
    char* U = ws + 26214400;
    unsigned short* Abuf    = (unsigned short*)(U);
    unsigned short* WqT_in  = (unsigned short*)(U + 7340032);
    unsigned short* WqT_ctx = (unsigned short*)(U + 13631488);
    unsigned short* Qb      = (unsigned short*)(U);
    unsigned short* Kb      = (unsigned short*)(U + 7340032);
    unsigned short* Vt      = (unsigned short*)(U + 14680064);
    unsigned short* Ob      = (unsigned short*)(U + 22020096);
    float* msb              = (float*)(ws + 62914560);
    float* lsb              = (float*)(ws + 63832064);
    if (ws_size < 64749568) return; // loud failure instead of corruption

    float* out_in  = (float*)d_out;
    float* out_ctx = out_in + (size_t)BB * L_IN * DIMSZ;

    conv_act<<<MROWS, 256, 0, stream>>>(input, context, Abuf);
    transp<<<dim3(16, 48), 256, 0, stream>>>(Wqkv_in,  WqT_in,  3072);
    transp<<<dim3(16, 48), 256, 0, stream>>>(Wqkv_ctx, WqT_ctx, 3072);
    transp<<<dim3(16, 16), 256, 0, stream>>>(Wo_in,  WoT_in,  1024);
    transp<<<dim3(16, 16), 256, 0, stream>>>(Wo_ctx, WoT_ctx, 1024);

    gemm2<3072, true, true><<<dim3(28, 24), 256, 0, stream>>>(
        Abuf, WqT_in, WqT_ctx, bqkv_in, bqkv_ctx, qkvb, qkvb);

    norm_rope_kernel<<<MROWS, 256, 0, stream>>>(
        qkvb, qw_in, kw_in, qw_ctx, kw_ctx, cosT, sinT, Qb, Kb, Vt);

    attn_kernel<<<dim3(BB * NHEADS, NTOT / 128, NSPLIT), 256, 0, stream>>>(
        Qb, Kb, Vt, mask, op0, op1, msb, lsb);

    attn_merge<<<3584, 256, 0, stream>>>(op0, op1, msb, lsb, Ob);

    gemm2<1024, false, false><<<dim3(28, 8), 256, 0, stream>>>(
        Ob, WoT_in, WoT_ctx, bo_in, bo_ctx, out_in, out_ctx);
}

// Round 8
// 192.071 us; speedup vs baseline: 1.2791x; 1.0366x over previous
//
#include <hip/hip_runtime.h>
#include <stdint.h>

#define DIMSZ 1024
#define NHEADS 16
#define HD 64
#define BB 2
#define L_IN 1536
#define L_CTX 256
#define NTOT 1792   // L_CTX + L_IN
#define MROWS 3584  // BB * NTOT
#define NSPLIT 4
#define KVSPAN (NTOT / NSPLIT)   // 448
#define NT64 (KVSPAN / 64)       // 7 tiles of 64 keys per split
#define NROWS_BH 57344           // 32 * NTOT

typedef __attribute__((ext_vector_type(8))) short bf16x8;
typedef __attribute__((ext_vector_type(4))) float f32x4;
typedef __attribute__((ext_vector_type(16))) float f32x16;

__device__ inline unsigned short f2bf(float f) {
    union { float f; unsigned u; } v; v.f = f;
    unsigned r = v.u + 0x7fffu + ((v.u >> 16) & 1u);
    return (unsigned short)(r >> 16);
}
__device__ inline float bf2f(unsigned short u) {
    union { float f; unsigned u; } v; v.u = ((unsigned)u) << 16; return v.f;
}

__device__ inline f32x4 zero4() {
    f32x4 v;
    #pragma unroll
    for (int i = 0; i < 4; i++) v[i] = 0.f;
    return v;
}
__device__ inline f32x16 zero16() {
    f32x16 v;
    #pragma unroll
    for (int i = 0; i < 16; i++) v[i] = 0.f;
    return v;
}

// async global->LDS, 16B per lane. LDS dest must be wave-uniform base + lane*16.
#define GLL16(g, l) __builtin_amdgcn_global_load_lds( \
    (const __attribute__((address_space(1))) unsigned int*)(g), \
    (__attribute__((address_space(3))) unsigned int*)(l), 16, 0, 0)

// ---------------------------------------------------------------------------
// Fused prep: blocks [0,3584) convert activations fp32->bf16 (qkv row order);
// blocks [3584,5632) transpose+convert the four weight matrices.
// ---------------------------------------------------------------------------
__global__ __launch_bounds__(256) void prep_kernel(
    const float* __restrict__ input, const float* __restrict__ context,
    unsigned short* __restrict__ Abuf,
    const float* __restrict__ Wq_in,  unsigned short* __restrict__ WqT_in,
    const float* __restrict__ Wq_ctx, unsigned short* __restrict__ WqT_ctx,
    const float* __restrict__ Wo_in,  unsigned short* __restrict__ WoT_in,
    const float* __restrict__ Wo_ctx, unsigned short* __restrict__ WoT_ctx)
{
    __shared__ unsigned short sm[64][65];
    int blk = blockIdx.x;
    int t = threadIdx.x;
    if (blk < 3584) {
        int e = (blk * 256 + t) * 4;
        int row = e >> 10, c = e & 1023;
        int b = row / NTOT, ln = row % NTOT;
        const float* src = (ln < L_CTX)
            ? context + ((size_t)b * L_CTX + ln) * 1024 + c
            : input   + ((size_t)b * L_IN + (ln - L_CTX)) * 1024 + c;
        float4 v = *(const float4*)src;
        ushort4 o; o.x = f2bf(v.x); o.y = f2bf(v.y); o.z = f2bf(v.z); o.w = f2bf(v.w);
        *(ushort4*)(Abuf + e) = o;
        return;
    }
    const float* W; unsigned short* Wt; int N; int tb;
    if (blk < 4352)      { W = Wq_in;  Wt = WqT_in;  N = 3072; tb = blk - 3584; }
    else if (blk < 5120) { W = Wq_ctx; Wt = WqT_ctx; N = 3072; tb = blk - 4352; }
    else if (blk < 5376) { W = Wo_in;  Wt = WoT_in;  N = 1024; tb = blk - 5120; }
    else                 { W = Wo_ctx; Wt = WoT_ctx; N = 1024; tb = blk - 5376; }
    int k0 = (tb & 15) * 64, n0 = (tb >> 4) * 64;
    #pragma unroll
    for (int i = 0; i < 4; i++) {
        int r = (t >> 4) + i * 16, c = (t & 15) * 4;
        float4 v = *(const float4*)(W + (size_t)(k0 + r) * N + n0 + c);
        sm[r][c] = f2bf(v.x); sm[r][c + 1] = f2bf(v.y);
        sm[r][c + 2] = f2bf(v.z); sm[r][c + 3] = f2bf(v.w);
    }
    __syncthreads();
    int rn = t & 63, kc = (t >> 6) * 16;
    unsigned short* dst = Wt + (size_t)(n0 + rn) * 1024 + k0 + kc;
    #pragma unroll
    for (int q = 0; q < 4; q++) {
        ushort4 o;
        o.x = sm[kc + q * 4 + 0][rn]; o.y = sm[kc + q * 4 + 1][rn];
        o.z = sm[kc + q * 4 + 2][rn]; o.w = sm[kc + q * 4 + 3][rn];
        *(ushort4*)(dst + q * 4) = o;
    }
}

// ---------------------------------------------------------------------------
// GEMM v2 (unchanged — verified): 128x128 tile, BK=64, global_load_lds
// staging with inverse-swizzled source + swizzled ds_read_b128 frags.
// ---------------------------------------------------------------------------
template<int NLD, bool OUT_BF16, bool IS_QKV>
__global__ __launch_bounds__(256, 4) void gemm2(
    const unsigned short* __restrict__ A,
    const unsigned short* __restrict__ Wt_in, const unsigned short* __restrict__ Wt_ctx,
    const float* __restrict__ bias_in, const float* __restrict__ bias_ctx,
    void* __restrict__ out_in_, void* __restrict__ out_ctx_)
{
    __shared__ __align__(16) unsigned short Asm[128 * 64];
    __shared__ __align__(16) unsigned short Bsm[128 * 64];
    const int rt = blockIdx.x, n0 = blockIdx.y * 128;
    const int b = rt / 14, lrt = rt % 14;
    const bool is_ctx = lrt < 2;
    const unsigned short* Wt = is_ctx ? Wt_ctx : Wt_in;
    const float* bias = is_ctx ? bias_ctx : bias_in;
    const int t = threadIdx.x, lane = t & 63, wid = t >> 6;
    const int wr = wid >> 1, wc = wid & 1;
    const int g4 = lane >> 4, l16 = lane & 15;

    const char* asrc[4]; const char* bsrc[4];
    #pragma unroll
    for (int j = 0; j < 4; j++) {
        int o = t * 16 + j * 4096;
        int row = o >> 7;
        int cb = (o & 127) ^ ((row & 7) << 4);
        asrc[j] = (const char*)A  + ((size_t)(rt * 128 + row)) * 2048 + cb;
        bsrc[j] = (const char*)Wt + ((size_t)(n0 + row)) * 2048 + cb;
    }

    f32x4 acc[4][4];
    #pragma unroll
    for (int mi = 0; mi < 4; mi++)
        #pragma unroll
        for (int ni = 0; ni < 4; ni++) acc[mi][ni] = zero4();

    for (int ks = 0; ks < 16; ks++) {
        __syncthreads();
        #pragma unroll
        for (int j = 0; j < 4; j++) {
            int o = t * 16 + j * 4096;
            GLL16(asrc[j], (char*)Asm + o);
            GLL16(bsrc[j], (char*)Bsm + o);
            asrc[j] += 128; bsrc[j] += 128;
        }
        __syncthreads();
        #pragma unroll
        for (int kk = 0; kk < 2; kk++) {
            bf16x8 a[4], bgf[4];
            #pragma unroll
            for (int mi = 0; mi < 4; mi++) {
                int row = wr * 64 + mi * 16 + l16;
                int byte = row * 128 + ((kk * 64 + g4 * 16) ^ ((row & 7) << 4));
                a[mi] = *(const bf16x8*)((const char*)Asm + byte);
            }
            #pragma unroll
            for (int ni = 0; ni < 4; ni++) {
                int col = wc * 64 + ni * 16 + l16;
                int byte = col * 128 + ((kk * 64 + g4 * 16) ^ ((col & 7) << 4));
                bgf[ni] = *(const bf16x8*)((const char*)Bsm + byte);
            }
            #pragma unroll
            for (int mi = 0; mi < 4; mi++)
                #pragma unroll
                for (int ni = 0; ni < 4; ni++)
                    acc[mi][ni] = __builtin_amdgcn_mfma_f32_16x16x32_bf16(
                        a[mi], bgf[ni], acc[mi][ni], 0, 0, 0);
        }
    }

    char* optr; size_t orow0;
    if constexpr (IS_QKV) {
        optr = (char*)out_in_; orow0 = (size_t)rt * 128;
    } else {
        if (is_ctx) { optr = (char*)out_ctx_; orow0 = (size_t)b * 256 + lrt * 128; }
        else        { optr = (char*)out_in_;  orow0 = (size_t)b * 1536 + (lrt - 2) * 128; }
    }
    #pragma unroll
    for (int mi = 0; mi < 4; mi++)
        #pragma unroll
        for (int ni = 0; ni < 4; ni++) {
            int col = n0 + wc * 64 + ni * 16 + l16;
            float bv = bias[col];
            #pragma unroll
            for (int r = 0; r < 4; r++) {
                size_t row = orow0 + wr * 64 + mi * 16 + g4 * 4 + r;
                float val = acc[mi][ni][r] + bv;
                if constexpr (OUT_BF16)
                    ((unsigned short*)optr)[row * NLD + col] = f2bf(val);
                else
                    ((float*)optr)[row * NLD + col] = val;
            }
        }
}

// ---------------------------------------------------------------------------
// Fused RMSNorm + weight + RoPE + scale + layout.
// Q prescale folds 0.125 * log2(e) (exp2-domain softmax downstream).
// ---------------------------------------------------------------------------
__global__ __launch_bounds__(256) void norm_rope_kernel(
    const unsigned short* __restrict__ qkv,
    const float* __restrict__ qw_in, const float* __restrict__ kw_in,
    const float* __restrict__ qw_ctx, const float* __restrict__ kw_ctx,
    const float* __restrict__ cosT, const float* __restrict__ sinT,
    unsigned short* __restrict__ Q, unsigned short* __restrict__ K,
    unsigned short* __restrict__ Vt)
{
    const float QSC = 0.125f * 1.44269504088896f;
    int bn = blockIdx.x;
    int b = bn / NTOT, n = bn % NTOT;
    int t = threadIdx.x;
    const unsigned short* row = qkv + (size_t)bn * 3072;
    ushort4 qu = *(const ushort4*)(row + t * 4);
    ushort4 ku = *(const ushort4*)(row + 1024 + t * 4);
    ushort4 vu = *(const ushort4*)(row + 2048 + t * 4);
    float q0f = bf2f(qu.x), q1f = bf2f(qu.y), q2f = bf2f(qu.z), q3f = bf2f(qu.w);
    float k0f = bf2f(ku.x), k1f = bf2f(ku.y), k2f = bf2f(ku.z), k3f = bf2f(ku.w);
    float sq = q0f * q0f + q1f * q1f + q2f * q2f + q3f * q3f;
    float sk = k0f * k0f + k1f * k1f + k2f * k2f + k3f * k3f;
    #pragma unroll
    for (int m = 1; m < 64; m <<= 1) { sq += __shfl_xor(sq, m); sk += __shfl_xor(sk, m); }
    __shared__ float redq[4], redk[4];
    int lane = t & 63, w = t >> 6;
    if (lane == 0) { redq[w] = sq; redk[w] = sk; }
    __syncthreads();
    sq = redq[0] + redq[1] + redq[2] + redq[3];
    sk = redk[0] + redk[1] + redk[2] + redk[3];
    float rsq = rsqrtf(sq * (1.f / 1024.f) + 1e-6f);
    float rsk = rsqrtf(sk * (1.f / 1024.f) + 1e-6f);
    bool is_ctx = (n < L_CTX);
    const float* qw = is_ctx ? qw_ctx : qw_in;
    const float* kw = is_ctx ? kw_ctx : kw_in;
    int col = t * 4;
    int h = col >> 6, d = col & 63;
    float c0 = cosT[n * 32 + (d >> 1)],     s0 = sinT[n * 32 + (d >> 1)];
    float c1 = cosT[n * 32 + (d >> 1) + 1], s1 = sinT[n * 32 + (d >> 1) + 1];
    size_t base = (((size_t)(b * NHEADS + h)) * NTOT + n) * HD + d;
    {
        float x0 = q0f * rsq * qw[col],     x1 = q1f * rsq * qw[col + 1];
        float x2 = q2f * rsq * qw[col + 2], x3 = q3f * rsq * qw[col + 3];
        float y0 = x0 * c0 - x1 * s0, y1 = x0 * s0 + x1 * c0;
        float y2 = x2 * c1 - x3 * s1, y3 = x2 * s1 + x3 * c1;
        ushort4 o; o.x = f2bf(y0 * QSC); o.y = f2bf(y1 * QSC);
        o.z = f2bf(y2 * QSC); o.w = f2bf(y3 * QSC);
        *(ushort4*)(Q + base) = o;
    }
    {
        float x0 = k0f * rsk * kw[col],     x1 = k1f * rsk * kw[col + 1];
        float x2 = k2f * rsk * kw[col + 2], x3 = k3f * rsk * kw[col + 3];
        float y0 = x0 * c0 - x1 * s0, y1 = x0 * s0 + x1 * c0;
        float y2 = x2 * c1 - x3 * s1, y3 = x2 * s1 + x3 * c1;
        ushort4 o; o.x = f2bf(y0); o.y = f2bf(y1); o.z = f2bf(y2); o.w = f2bf(y3);
        *(ushort4*)(K + base) = o;
    }
    size_t vb = ((size_t)(b * NHEADS + h)) * HD;
    Vt[(vb + d + 0) * NTOT + n] = vu.x;
    Vt[(vb + d + 1) * NTOT + n] = vu.y;
    Vt[(vb + d + 2) * NTOT + n] = vu.z;
    Vt[(vb + d + 3) * NTOT + n] = vu.w;
}

// ---------------------------------------------------------------------------
// Flash attention v6: 64-key LDS tiles (XOR-8 swizzle both K and V), staged
// via global_load_lds; double-buffered, one barrier per tile; NSPLIT=4;
// exp2-domain softmax; setprio around MFMA clusters.
// ---------------------------------------------------------------------------
__global__ __launch_bounds__(256) void attn_kernel(
    const unsigned short* __restrict__ Q, const unsigned short* __restrict__ K,
    const unsigned short* __restrict__ Vt, const int* __restrict__ mask,
    unsigned short* __restrict__ op0, unsigned short* __restrict__ op1,
    unsigned short* __restrict__ op2, unsigned short* __restrict__ op3,
    float* __restrict__ ms, float* __restrict__ ls)
{
    // [buf0: K 8K | V 8K][buf1: K 8K | V 8K][mbias 1K]
    __shared__ __align__(16) char smem[33792];
    float* mbias = (float*)(smem + 32768);
    int bh = blockIdx.x;
    int b = bh >> 4;
    int s = blockIdx.z;
    int t = threadIdx.x, lane = t & 63, wid = t >> 6;
    int g = lane >> 5, lq = lane & 31;
    int q0 = blockIdx.y * 128 + wid * 32;

    const unsigned short* Qp = Q + (size_t)bh * NTOT * HD;
    const char* Kbase = (const char*)(K + (size_t)bh * NTOT * HD);
    const char* Vbase = (const char*)(Vt + (size_t)bh * HD * NTOT);
    const int kvbeg = s * KVSPAN;

    int srow = wid * 8 + (lane >> 3);
    int srcb = ((lane & 7) * 16) ^ ((lane >> 3) << 4);
    const char* ks0 = Kbase + (size_t)(kvbeg + srow) * 128 + srcb;
    const char* ks1 = ks0 + 32 * 128;
    const char* vs0 = Vbase + (size_t)srow * (NTOT * 2) + (size_t)kvbeg * 2 + srcb;
    const char* vs1 = vs0 + (size_t)32 * (NTOT * 2);
    const int sdst = wid * 1024 + lane * 16;

    auto stage = [&](int bufbase, int tt) {
        GLL16(ks0 + (size_t)tt * 8192, smem + bufbase + sdst);
        GLL16(ks1 + (size_t)tt * 8192, smem + bufbase + 4096 + sdst);
        GLL16(vs0 + (size_t)tt * 128,  smem + bufbase + 8192 + sdst);
        GLL16(vs1 + (size_t)tt * 128,  smem + bufbase + 8192 + 4096 + sdst);
    };

    stage(0, 0);
    if (t < L_CTX) mbias[t] = mask[b * L_CTX + t] ? 0.f : -1e30f;

    bf16x8 qf[4];
    #pragma unroll
    for (int kk = 0; kk < 4; kk++)
        qf[kk] = *(const bf16x8*)(Qp + (size_t)(q0 + lq) * HD + kk * 16 + g * 8);

    f32x16 oacc0 = zero16(), oacc1 = zero16();
    float mrun = -1e30f, denom = 0.f;
    const int ksw = (lq & 7) << 4;

    auto pack2 = [&](const f32x16& p, bf16x8* pfo) {
        #pragma unroll
        for (int kk = 0; kk < 2; kk++) {
            unsigned a1, b1, a2, b2;
            asm("v_cvt_pk_bf16_f32 %0, %1, %2" : "=v"(a1) : "v"(p[8 * kk + 0]), "v"(p[8 * kk + 1]));
            asm("v_cvt_pk_bf16_f32 %0, %1, %2" : "=v"(a2) : "v"(p[8 * kk + 2]), "v"(p[8 * kk + 3]));
            asm("v_cvt_pk_bf16_f32 %0, %1, %2" : "=v"(b1) : "v"(p[8 * kk + 4]), "v"(p[8 * kk + 5]));
            asm("v_cvt_pk_bf16_f32 %0, %1, %2" : "=v"(b2) : "v"(p[8 * kk + 6]), "v"(p[8 * kk + 7]));
            unsigned sa1 = __shfl_xor(a1, 32), sb1 = __shfl_xor(b1, 32);
            unsigned sa2 = __shfl_xor(a2, 32), sb2 = __shfl_xor(b2, 32);
            union { unsigned u[4]; bf16x8 v; } pu;
            pu.u[0] = g ? sb1 : a1;
            pu.u[1] = g ? sb2 : a2;
            pu.u[2] = g ? b1 : sa1;
            pu.u[3] = g ? b2 : sa2;
            pfo[kk] = pu.v;
        }
    };

    auto compute = [&](const char* bufK, const char* bufV, int kv0, bool msk) {
        f32x16 st0 = zero16(), st1 = zero16();
        __builtin_amdgcn_s_setprio(1);
        #pragma unroll
        for (int kk = 0; kk < 4; kk++) {
            int off = (kk * 32 + g * 16) ^ ksw;
            bf16x8 kf0 = *(const bf16x8*)(bufK + lq * 128 + off);
            bf16x8 kf1 = *(const bf16x8*)(bufK + (lq + 32) * 128 + off);
            st0 = __builtin_amdgcn_mfma_f32_32x32x16_bf16(kf0, qf[kk], st0, 0, 0, 0);
            st1 = __builtin_amdgcn_mfma_f32_32x32x16_bf16(kf1, qf[kk], st1, 0, 0, 0);
        }
        __builtin_amdgcn_s_setprio(0);
        if (msk) {
            #pragma unroll
            for (int r = 0; r < 16; r++) {
                int crow = (r & 3) + 8 * (r >> 2) + 4 * g;
                st0[r] += mbias[kv0 + crow];
                st1[r] += mbias[kv0 + 32 + crow];
            }
        }
        float tmax = -1e30f;
        #pragma unroll
        for (int r = 0; r < 16; r++) tmax = fmaxf(tmax, fmaxf(st0[r], st1[r]));
        tmax = fmaxf(tmax, __shfl_xor(tmax, 32));
        if (!__all(tmax - mrun <= 8.f)) {
            float mnew = fmaxf(mrun, tmax);
            float corr = exp2f(mrun - mnew);
            denom *= corr; mrun = mnew;
            #pragma unroll
            for (int i = 0; i < 16; i++) { oacc0[i] *= corr; oacc1[i] *= corr; }
        }
        float psum = 0.f;
        #pragma unroll
        for (int r = 0; r < 16; r++) { st0[r] = exp2f(st0[r] - mrun); psum += st0[r]; }
        #pragma unroll
        for (int r = 0; r < 16; r++) { st1[r] = exp2f(st1[r] - mrun); psum += st1[r]; }
        psum += __shfl_xor(psum, 32);
        denom += psum;
        bf16x8 pf[4];
        pack2(st0, pf);
        pack2(st1, pf + 2);
        __builtin_amdgcn_s_setprio(1);
        #pragma unroll
        for (int kk = 0; kk < 4; kk++) {
            int off = (kk * 32 + g * 16) ^ ksw;
            bf16x8 va = *(const bf16x8*)(bufV + lq * 128 + off);
            bf16x8 vb = *(const bf16x8*)(bufV + (lq + 32) * 128 + off);
            oacc0 = __builtin_amdgcn_mfma_f32_32x32x16_bf16(va, pf[kk], oacc0, 0, 0, 0);
            oacc1 = __builtin_amdgcn_mfma_f32_32x32x16_bf16(vb, pf[kk], oacc1, 0, 0, 0);
        }
        __builtin_amdgcn_s_setprio(0);
    };

    __syncthreads();

    #pragma unroll 1
    for (int tt = 0; tt < NT64; tt++) {
        int curb = (tt & 1) * 16384;
        if (tt + 1 < NT64) stage(16384 - curb, tt + 1);
        compute(smem + curb, smem + curb + 8192, kvbeg + tt * 64, (s == 0) && (tt < 4));
        __syncthreads();
    }

    float inv = (denom > 0.f) ? 1.0f / denom : 0.f;
    int n = q0 + lq;
    int prow = bh * NTOT + n;
    unsigned short* op = (s == 0) ? op0 : (s == 1) ? op1 : (s == 2) ? op2 : op3;
    size_t obase = (size_t)prow * 64;
    #pragma unroll
    for (int r = 0; r < 16; r++) {
        int d = (r & 3) + 8 * (r >> 2) + 4 * g;
        op[obase + d] = f2bf(oacc0[r] * inv);
        op[obase + 32 + d] = f2bf(oacc1[r] * inv);
    }
    if (g == 0) {
        ms[s * NROWS_BH + prow] = mrun;
        ls[s * NROWS_BH + prow] = denom;
    }
}

// ---------------------------------------------------------------------------
// Merge NSPLIT=4 partials -> Ob bf16 (B, NTOT, 1024). grid = 3584.
// Stats in exp2 (log2) domain.
// ---------------------------------------------------------------------------
__global__ __launch_bounds__(256) void attn_merge(
    const unsigned short* __restrict__ op0, const unsigned short* __restrict__ op1,
    const unsigned short* __restrict__ op2, const unsigned short* __restrict__ op3,
    const float* __restrict__ ms, const float* __restrict__ ls,
    unsigned short* __restrict__ Ob)
{
    int u = blockIdx.x * 256 + threadIdx.x;
    int dg = u & 15, bhn = u >> 4;
    int bh = bhn / NTOT, n = bhn % NTOT;
    int b = bh >> 4, h = bh & 15;
    float m0 = ms[bhn], m1 = ms[NROWS_BH + bhn];
    float m2 = ms[2 * NROWS_BH + bhn], m3 = ms[3 * NROWS_BH + bhn];
    float l0 = ls[bhn], l1 = ls[NROWS_BH + bhn];
    float l2 = ls[2 * NROWS_BH + bhn], l3 = ls[3 * NROWS_BH + bhn];
    float M = fmaxf(fmaxf(m0, m1), fmaxf(m2, m3));
    float w0 = l0 * exp2f(m0 - M), w1 = l1 * exp2f(m1 - M);
    float w2 = l2 * exp2f(m2 - M), w3 = l3 * exp2f(m3 - M);
    float inv = 1.f / (w0 + w1 + w2 + w3);
    w0 *= inv; w1 *= inv; w2 *= inv; w3 *= inv;
    size_t ro = (size_t)bhn * 64 + dg * 4;
    ushort4 a0 = *(const ushort4*)(op0 + ro);
    ushort4 a1 = *(const ushort4*)(op1 + ro);
    ushort4 a2 = *(const ushort4*)(op2 + ro);
    ushort4 a3 = *(const ushort4*)(op3 + ro);
    ushort4 o;
    o.x = f2bf(w0 * bf2f(a0.x) + w1 * bf2f(a1.x) + w2 * bf2f(a2.x) + w3 * bf2f(a3.x));
    o.y = f2bf(w0 * bf2f(a0.y) + w1 * bf2f(a1.y) + w2 * bf2f(a2.y) + w3 * bf2f(a3.y));
    o.z = f2bf(w0 * bf2f(a0.z) + w1 * bf2f(a1.z) + w2 * bf2f(a2.z) + w3 * bf2f(a3.z));
    o.w = f2bf(w0 * bf2f(a0.w) + w1 * bf2f(a1.w) + w2 * bf2f(a2.w) + w3 * bf2f(a3.w));
    size_t ob = ((size_t)(b * NTOT + n)) * 1024 + h * 64 + dg * 4;
    *(ushort4*)(Ob + ob) = o;
}

// ---------------------------------------------------------------------------
extern "C" void kernel_launch(void* const* d_in, const int* in_sizes, int n_in,
                              void* d_out, int out_size, void* d_ws, size_t ws_size,
                              hipStream_t stream) {
    const float* input    = (const float*)d_in[0];
    const float* context  = (const float*)d_in[1];
    const float* cosT     = (const float*)d_in[2];
    const float* sinT     = (const float*)d_in[3];
    const float* Wqkv_in  = (const float*)d_in[4];
    const float* bqkv_in  = (const float*)d_in[5];
    const float* Wqkv_ctx = (const float*)d_in[6];
    const float* bqkv_ctx = (const float*)d_in[7];
    const float* qw_in    = (const float*)d_in[8];
    const float* kw_in    = (const float*)d_in[9];
    const float* qw_ctx   = (const float*)d_in[10];
    const float* kw_ctx   = (const float*)d_in[11];
    const float* Wo_in    = (const float*)d_in[12];
    const float* bo_in    = (const float*)d_in[13];
    const float* Wo_ctx   = (const float*)d_in[14];
    const float* bo_ctx   = (const float*)d_in[15];
    const int*   mask     = (const int*)d_in[16];

    char* ws = (char*)d_ws;
    unsigned short* WoT_in  = (unsigned short*)(ws);
    unsigned short* WoT_ctx = (unsigned short*)(ws + 2097152);
    unsigned short* qkvb    = (unsigned short*)(ws + 4194304);
    unsigned short* op0     = (unsigned short*)(ws + 4194304);
    unsigned short* op1     = (unsigned short*)(ws + 11534336);
    unsigned short* op2     = (unsigned short*)(ws + 18874368);
    char* U = ws + 26214400;
    unsigned short* Abuf    = (unsigned short*)(U);
    unsigned short* WqT_in  = (unsigned short*)(U + 7340032);
    unsigned short* WqT_ctx = (unsigned short*)(U + 13631488);
    unsigned short* Qb      = (unsigned short*)(U);
    unsigned short* Kb      = (unsigned short*)(U + 7340032);
    unsigned short* Vt      = (unsigned short*)(U + 14680064);
    unsigned short* Ob      = (unsigned short*)(U + 22020096);
    unsigned short* op3     = (unsigned short*)(ws + 55574528);
    float* msb              = (float*)(ws + 62914560);
    float* lsb              = (float*)(ws + 63832064);
    if (ws_size < 64749568) return; // loud failure instead of corruption

    float* out_in  = (float*)d_out;
    float* out_ctx = out_in + (size_t)BB * L_IN * DIMSZ;

    prep_kernel<<<5632, 256, 0, stream>>>(
        input, context, Abuf,
        Wqkv_in, WqT_in, Wqkv_ctx, WqT_ctx, Wo_in, WoT_in, Wo_ctx, WoT_ctx);

    gemm2<3072, true, true><<<dim3(28, 24), 256, 0, stream>>>(
        Abuf, WqT_in, WqT_ctx, bqkv_in, bqkv_ctx, qkvb, qkvb);

    norm_rope_kernel<<<MROWS, 256, 0, stream>>>(
        qkvb, qw_in, kw_in, qw_ctx, kw_ctx, cosT, sinT, Qb, Kb, Vt);

    attn_kernel<<<dim3(BB * NHEADS, NTOT / 128, NSPLIT), 256, 0, stream>>>(
        Qb, Kb, Vt, mask, op0, op1, op2, op3, msb, lsb);

    attn_merge<<<3584, 256, 0, stream>>>(op0, op1, op2, op3, msb, lsb, Ob);

    gemm2<1024, false, false><<<dim3(28, 8), 256, 0, stream>>>(
        Ob, WoT_in, WoT_ctx, bo_in, bo_ctx, out_in, out_ctx);
}